// Round 2
// baseline (891.891 us; speedup 1.0000x reference)
//
#include <hip/hip_runtime.h>
#include <hip/hip_bf16.h>

typedef __bf16 bf16;
typedef __attribute__((ext_vector_type(8))) __bf16 bf16x8;
typedef __attribute__((ext_vector_type(4))) float f32x4;

#define S_LEN 2048
#define DM 2048
#define NH 32
#define HD 64
#define QKV_LD 6144
#define SCALE_F 0.125f

// Load 8 contiguous elements as bf16x8, converting from f32 if needed.
template <typename T>
__device__ __forceinline__ bf16x8 load8(const T* __restrict__ p) {
  if constexpr (__is_same(T, float)) {
    const f32x4 a = *(const f32x4*)p;
    const f32x4 b = *(const f32x4*)(p + 4);
    bf16x8 r;
    r[0] = (bf16)a[0]; r[1] = (bf16)a[1]; r[2] = (bf16)a[2]; r[3] = (bf16)a[3];
    r[4] = (bf16)b[0]; r[5] = (bf16)b[1]; r[6] = (bf16)b[2]; r[7] = (bf16)b[3];
    return r;
  } else {
    return *(const bf16x8*)p;
  }
}

// ---------------------------------------------------------------------------
// GEMM: C[M][N] = A[M][K] @ W[N][K]^T + bias[N]   (f32 accum, bf16 MFMA)
// 128x128 tile, BK=32, 4 waves (2x2), each wave 64x64 via 4x4 16x16x32 MFMA.
// Reg-staged LDS (single buffer, 2 barriers/K-step) — correctness-first.
// ---------------------------------------------------------------------------
template <typename TA, typename TW, typename TO>
__global__ __launch_bounds__(256) void gemm_bias_bt(
    const TA* __restrict__ A, const TW* __restrict__ W,
    const float* __restrict__ bias, TO* __restrict__ C,
    const int M, const int N, const int K)
{
  __shared__ __align__(16) bf16 As[128 * 32];
  __shared__ __align__(16) bf16 Bs[128 * 32];
  const int tid  = threadIdx.x;
  const int lane = tid & 63;
  const int wid  = tid >> 6;
  const int wr = wid >> 1, wc = wid & 1;
  const int row0 = blockIdx.y << 7, col0 = blockIdx.x << 7;
  const int lq = lane & 15, seg = lane >> 4;

  const f32x4 fzero = {0.f, 0.f, 0.f, 0.f};
  f32x4 acc[4][4];
#pragma unroll
  for (int i = 0; i < 4; ++i)
#pragma unroll
    for (int j = 0; j < 4; ++j) acc[i][j] = fzero;

  const int nk = K >> 5;
  for (int kt = 0; kt < nk; ++kt) {
    const int k0 = kt << 5;
    bf16x8 av[2], wv[2];
#pragma unroll
    for (int c = 0; c < 2; ++c) {
      const int idx = (c << 8) + tid;       // 0..511
      const int r = idx >> 2, ch = idx & 3; // row 0..127, 8-elem chunk 0..3
      av[c] = load8<TA>(A + (size_t)(row0 + r) * K + (k0 + ch * 8));
      wv[c] = load8<TW>(W + (size_t)(col0 + r) * K + (k0 + ch * 8));
    }
    __syncthreads();   // all waves done reading LDS from previous K-step
#pragma unroll
    for (int c = 0; c < 2; ++c) {
      const int idx = (c << 8) + tid;
      *(bf16x8*)(As + idx * 8) = av[c];
      *(bf16x8*)(Bs + idx * 8) = wv[c];
    }
    __syncthreads();   // tiles ready
    bf16x8 af[4], bfr[4];
#pragma unroll
    for (int i = 0; i < 4; ++i) {
      af[i]  = *(const bf16x8*)(As + ((wr << 6) + (i << 4) + lq) * 32 + seg * 8);
      bfr[i] = *(const bf16x8*)(Bs + ((wc << 6) + (i << 4) + lq) * 32 + seg * 8);
    }
#pragma unroll
    for (int i = 0; i < 4; ++i)
#pragma unroll
      for (int j = 0; j < 4; ++j)
        acc[i][j] = __builtin_amdgcn_mfma_f32_16x16x32_bf16(af[i], bfr[j], acc[i][j], 0, 0, 0);
  }

  // Epilogue: C/D layout row=(lane>>4)*4+r, col=lane&15 (m89/m91-verified)
#pragma unroll
  for (int j = 0; j < 4; ++j) {
    const int col = col0 + (wc << 6) + (j << 4) + lq;
    const float bv = bias[col];
#pragma unroll
    for (int i = 0; i < 4; ++i) {
      const int rbase = row0 + (wr << 6) + (i << 4) + (seg << 2);
#pragma unroll
      for (int r = 0; r < 4; ++r)
        C[(size_t)(rbase + r) * N + col] = (TO)(acc[i][j][r] + bv);
    }
  }
}

// ---------------------------------------------------------------------------
// Causal attention. Block = (qb, h): 16 query rows of one head, 256 threads.
// Phase A: scores S[16][<=2048] = Q K^T * scale into LDS f32 (causal-masked).
// Phase B: wave-parallel softmax per row (unnormalized exp, 1/sum deferred).
// Phase C: O = P V via MFMA, scaled by 1/sum in epilogue.
// ---------------------------------------------------------------------------
__global__ __launch_bounds__(256) void attn_causal(
    const bf16* __restrict__ qkv, bf16* __restrict__ out)
{
  __shared__ float sc[16][2052];  // +4 pad: breaks bank aliasing on PV reads
  __shared__ float rinv[16];
  const int qb  = blockIdx.x;     // 0..127
  const int h   = blockIdx.y;     // 0..31
  const int tid = threadIdx.x;
  const int lane = tid & 63;
  const int wid  = tid >> 6;
  const int lq = lane & 15, seg = lane >> 4;
  const f32x4 fzero = {0.f, 0.f, 0.f, 0.f};

  const bf16* Q = qkv + (size_t)(qb * 16) * QKV_LD + h * HD;
  const bf16* K = qkv + DM + h * HD;
  const bf16* V = qkv + 2 * DM + h * HD;

  // Q fragments (A-operand), hoisted: rows lq, k-dim = head_dim 64 (2 steps)
  const bf16x8 qf0 = *(const bf16x8*)(Q + (size_t)lq * QKV_LD + seg * 8);
  const bf16x8 qf1 = *(const bf16x8*)(Q + (size_t)lq * QKV_LD + 32 + seg * 8);

  // ---- Phase A: QK^T over causal tiles, round-robin across 4 waves
  const int ntiles = qb + 1;
  for (int nt = wid; nt < ntiles; nt += 4) {
    const bf16* Kr = K + (size_t)(nt * 16 + lq) * QKV_LD;
    const bf16x8 kf0 = *(const bf16x8*)(Kr + seg * 8);
    const bf16x8 kf1 = *(const bf16x8*)(Kr + 32 + seg * 8);
    f32x4 a = fzero;
    a = __builtin_amdgcn_mfma_f32_16x16x32_bf16(qf0, kf0, a, 0, 0, 0);
    a = __builtin_amdgcn_mfma_f32_16x16x32_bf16(qf1, kf1, a, 0, 0, 0);
    const int col = nt * 16 + lq;
#pragma unroll
    for (int r = 0; r < 4; ++r) {
      const int qr = seg * 4 + r;
      sc[qr][col] = (col <= qb * 16 + qr) ? a[r] * SCALE_F : -1e30f;
    }
  }
  __syncthreads();

  // ---- Phase B: softmax (one wave per row, 4 rows per wave)
  const int Lpad = ntiles * 16;
#pragma unroll
  for (int rr = 0; rr < 4; ++rr) {
    const int row = wid * 4 + rr;
    const int L = qb * 16 + row + 1;   // valid length (causal)
    float m = -1e30f;
    for (int i = lane; i < L; i += 64) m = fmaxf(m, sc[row][i]);
#pragma unroll
    for (int o = 32; o >= 1; o >>= 1) m = fmaxf(m, __shfl_xor(m, o));
    float s = 0.f;
    for (int i = lane; i < Lpad; i += 64) {  // masked entries: exp(-1e30)=0
      const float e = __expf(sc[row][i] - m);
      sc[row][i] = e;
      s += e;
    }
#pragma unroll
    for (int o = 32; o >= 1; o >>= 1) s += __shfl_xor(s, o);
    if (lane == 0) rinv[row] = 1.f / s;
  }
  __syncthreads();

  // ---- Phase C: O[16][64] = P[16][Lpad] @ V[Lpad][64]; wave w owns d-tile w
  f32x4 oa = fzero;
  const int nkk = (Lpad + 31) >> 5;
  for (int kk = 0; kk < nkk; ++kk) {
    const int kbase = (kk << 5) + seg * 8;
    bf16x8 pa, vb;
#pragma unroll
    for (int j = 0; j < 8; ++j) {
      const int k = kbase + j;
      const bool ok = (k < Lpad);
      pa[j] = (bf16)(ok ? sc[lq][k] : 0.f);
      vb[j] = ok ? V[(size_t)k * QKV_LD + wid * 16 + lq] : (bf16)0.f;
    }
    oa = __builtin_amdgcn_mfma_f32_16x16x32_bf16(pa, vb, oa, 0, 0, 0);
  }
#pragma unroll
  for (int r = 0; r < 4; ++r) {
    const int qr = seg * 4 + r;
    out[(size_t)(qb * 16 + qr) * DM + h * HD + wid * 16 + lq] =
        (bf16)(oa[r] * rinv[qr]);
  }
}

// ---------------------------------------------------------------------------
extern "C" void kernel_launch(void* const* d_in, const int* in_sizes, int n_in,
                              void* d_out, int out_size, void* d_ws, size_t ws_size,
                              hipStream_t stream) {
  (void)in_sizes; (void)n_in; (void)out_size; (void)ws_size;
  const float* hidden = (const float*)d_in[0];
  const float* w_qkv  = (const float*)d_in[1];
  const float* b_qkv  = (const float*)d_in[2];
  const float* w_out  = (const float*)d_in[3];
  const float* b_out  = (const float*)d_in[4];
  float* out = (float*)d_out;

  bf16* qkvbuf  = (bf16*)d_ws;                          // [2048][6144] bf16
  bf16* attnbuf = qkvbuf + (size_t)S_LEN * (3 * DM);    // [2048][2048] bf16

  dim3 blk(256);
  // QKV projection: M=2048, N=6144, K=2048
  gemm_bias_bt<float, float, bf16><<<dim3(48, 16), blk, 0, stream>>>(
      hidden, w_qkv, b_qkv, qkvbuf, S_LEN, 3 * DM, DM);
  // Causal attention per (16-query block, head)
  attn_causal<<<dim3(128, NH), blk, 0, stream>>>(qkvbuf, attnbuf);
  // Output projection: M=2048, N=2048, K=2048
  gemm_bias_bt<bf16, float, float><<<dim3(16, 16), blk, 0, stream>>>(
      attnbuf, w_out, b_out, out, S_LEN, DM, DM);
}

// Round 3
// 275.753 us; speedup vs baseline: 3.2344x; 3.2344x over previous
//
#include <hip/hip_runtime.h>
#include <hip/hip_bf16.h>

typedef __bf16 bf16;
typedef __attribute__((ext_vector_type(8))) __bf16 bf16x8;
typedef __attribute__((ext_vector_type(4))) float f32x4;

#define S_LEN 2048
#define DM 2048
#define NH 32
#define HD 64
#define QKV_LD 6144
#define SCALE_F 0.125f

// Load 8 contiguous elements as bf16x8, converting from f32 if needed.
template <typename T>
__device__ __forceinline__ bf16x8 load8(const T* __restrict__ p) {
  if constexpr (__is_same(T, float)) {
    const f32x4 a = *(const f32x4*)p;
    const f32x4 b = *(const f32x4*)(p + 4);
    bf16x8 r;
    r[0] = (bf16)a[0]; r[1] = (bf16)a[1]; r[2] = (bf16)a[2]; r[3] = (bf16)a[3];
    r[4] = (bf16)b[0]; r[5] = (bf16)b[1]; r[6] = (bf16)b[2]; r[7] = (bf16)b[3];
    return r;
  } else {
    return *(const bf16x8*)p;
  }
}

// ---------------------------------------------------------------------------
// GEMM: C[M][N] = A[M][K] @ W[N][K]^T + bias[N]   (f32 accum, bf16 MFMA)
// 128x128 tile, BK=32, 4 waves (2x2), each wave 64x64 via 4x4 16x16x32 MFMA.
// ---------------------------------------------------------------------------
template <typename TA, typename TW, typename TO>
__global__ __launch_bounds__(256) void gemm_bias_bt(
    const TA* __restrict__ A, const TW* __restrict__ W,
    const float* __restrict__ bias, TO* __restrict__ C,
    const int M, const int N, const int K)
{
  __shared__ __align__(16) bf16 As[128 * 32];
  __shared__ __align__(16) bf16 Bs[128 * 32];
  const int tid  = threadIdx.x;
  const int lane = tid & 63;
  const int wid  = tid >> 6;
  const int wr = wid >> 1, wc = wid & 1;
  const int row0 = blockIdx.y << 7, col0 = blockIdx.x << 7;
  const int lq = lane & 15, seg = lane >> 4;

  const f32x4 fzero = {0.f, 0.f, 0.f, 0.f};
  f32x4 acc[4][4];
#pragma unroll
  for (int i = 0; i < 4; ++i)
#pragma unroll
    for (int j = 0; j < 4; ++j) acc[i][j] = fzero;

  const int nk = K >> 5;
  for (int kt = 0; kt < nk; ++kt) {
    const int k0 = kt << 5;
    bf16x8 av[2], wv[2];
#pragma unroll
    for (int c = 0; c < 2; ++c) {
      const int idx = (c << 8) + tid;       // 0..511
      const int r = idx >> 2, ch = idx & 3; // row 0..127, 8-elem chunk 0..3
      av[c] = load8<TA>(A + (size_t)(row0 + r) * K + (k0 + ch * 8));
      wv[c] = load8<TW>(W + (size_t)(col0 + r) * K + (k0 + ch * 8));
    }
    __syncthreads();
#pragma unroll
    for (int c = 0; c < 2; ++c) {
      const int idx = (c << 8) + tid;
      *(bf16x8*)(As + idx * 8) = av[c];
      *(bf16x8*)(Bs + idx * 8) = wv[c];
    }
    __syncthreads();
    bf16x8 af[4], bfr[4];
#pragma unroll
    for (int i = 0; i < 4; ++i) {
      af[i]  = *(const bf16x8*)(As + ((wr << 6) + (i << 4) + lq) * 32 + seg * 8);
      bfr[i] = *(const bf16x8*)(Bs + ((wc << 6) + (i << 4) + lq) * 32 + seg * 8);
    }
#pragma unroll
    for (int i = 0; i < 4; ++i)
#pragma unroll
      for (int j = 0; j < 4; ++j)
        acc[i][j] = __builtin_amdgcn_mfma_f32_16x16x32_bf16(af[i], bfr[j], acc[i][j], 0, 0, 0);
  }

#pragma unroll
  for (int j = 0; j < 4; ++j) {
    const int col = col0 + (wc << 6) + (j << 4) + lq;
    const float bv = bias[col];
#pragma unroll
    for (int i = 0; i < 4; ++i) {
      const int rbase = row0 + (wr << 6) + (i << 4) + (seg << 2);
#pragma unroll
      for (int r = 0; r < 4; ++r)
        C[(size_t)(rbase + r) * N + col] = (TO)(acc[i][j][r] + bv);
    }
  }
}

// ---------------------------------------------------------------------------
// Flash-style causal attention. Block = (64-query tile, head), 4 waves.
// Wave w owns query rows qb*64 + w*16 .. +15. KV tiles of 64 keys staged in
// LDS (K row-major swizzled, V transposed swizzled), online softmax in regs.
// ---------------------------------------------------------------------------
__global__ __launch_bounds__(256) void attn_flash(
    const bf16* __restrict__ qkv, bf16* __restrict__ out)
{
  __shared__ __align__(16) bf16 Ks[64][64];       // [key][d], col-swizzled
  __shared__ __align__(16) bf16 Vt[64][64];       // [d][key], key-swizzled
  __shared__ __align__(16) bf16 Ps[4][16][64];    // per-wave P, col-swizzled
  const int qb  = (int)gridDim.x - 1 - (int)blockIdx.x;  // big blocks first
  const int h   = blockIdx.y;
  const int tid = threadIdx.x;
  const int lane = tid & 63, wid = tid >> 6;
  const int lq = lane & 15, seg = lane >> 4;

  const bf16* Qg = qkv + (size_t)(qb * 64 + wid * 16) * QKV_LD + h * HD;
  const bf16* Kg = qkv + DM + h * HD;
  const bf16* Vg = qkv + 2 * DM + h * HD;

  // Q A-fragments: row lq of this wave's 16-query slice, k = d
  bf16x8 qf[2];
  qf[0] = *(const bf16x8*)(Qg + (size_t)lq * QKV_LD + seg * 8);
  qf[1] = *(const bf16x8*)(Qg + (size_t)lq * QKV_LD + 32 + seg * 8);

  const f32x4 fz = {0.f, 0.f, 0.f, 0.f};
  f32x4 o[4] = {fz, fz, fz, fz};    // O[q=seg*4+r][d=dt*16+lq]
  float m[4], l[4];
#pragma unroll
  for (int r = 0; r < 4; ++r) { m[r] = -1e30f; l[r] = 0.f; }

  const int srow = tid >> 3, sch = tid & 7;  // staging: row, 8-elem chunk

  for (int nt = 0; nt <= qb; ++nt) {
    __syncthreads();   // previous tile's reads complete
    // ---- stage K (swizzled rows) and V (transposed, swizzled keys)
#pragma unroll
    for (int c = 0; c < 2; ++c) {
      const int row = (c << 5) + srow;     // 0..63
      const bf16* src = (const bf16*)0;
      const bf16x8 kv = *(const bf16x8*)(Kg + (size_t)((nt << 6) + row) * QKV_LD + (sch << 3));
      const bf16x8 vv = *(const bf16x8*)(Vg + (size_t)((nt << 6) + row) * QKV_LD + (sch << 3));
      (void)src;
      *(bf16x8*)(&Ks[row][(sch ^ (row & 7)) << 3]) = kv;
#pragma unroll
      for (int j = 0; j < 8; ++j) {
        const int keyp = row ^ ((j ^ sch) << 3);   // xorv(d)=(d&7)^((d>>3)&7)
        Vt[(sch << 3) + j][keyp] = vv[j];
      }
    }
    __syncthreads();   // tiles ready

    // ---- QK^T: scores S[q=seg*4+r][key=ct*16+lq]
    f32x4 s[4];
#pragma unroll
    for (int ct = 0; ct < 4; ++ct) {
      s[ct] = fz;
#pragma unroll
      for (int ks = 0; ks < 2; ++ks) {
        const int blk = ((ks << 2) + seg) ^ (lq & 7);
        const bf16x8 kf = *(const bf16x8*)(&Ks[(ct << 4) + lq][blk << 3]);
        s[ct] = __builtin_amdgcn_mfma_f32_16x16x32_bf16(qf[ks], kf, s[ct], 0, 0, 0);
      }
    }

    // ---- scale + causal mask (diagonal tile only)
    const bool diag = (nt == qb);
#pragma unroll
    for (int ct = 0; ct < 4; ++ct) {
      const int key = (nt << 6) + (ct << 4) + lq;
#pragma unroll
      for (int r = 0; r < 4; ++r) {
        float v = s[ct][r] * SCALE_F;
        if (diag) {
          const int qrow = (qb << 6) + (wid << 4) + (seg << 2) + r;
          if (key > qrow) v = -1e30f;
        }
        s[ct][r] = v;
      }
    }

    // ---- online softmax update (row-reduce over lq lanes)
    float sc_f[4];
#pragma unroll
    for (int r = 0; r < 4; ++r) {
      float tm = fmaxf(fmaxf(s[0][r], s[1][r]), fmaxf(s[2][r], s[3][r]));
#pragma unroll
      for (int off = 8; off >= 1; off >>= 1) tm = fmaxf(tm, __shfl_xor(tm, off));
      const float mn = fmaxf(m[r], tm);
      sc_f[r] = __expf(m[r] - mn);
      m[r] = mn;
    }
#pragma unroll
    for (int r = 0; r < 4; ++r) {
      float rs = 0.f;
#pragma unroll
      for (int ct = 0; ct < 4; ++ct) {
        const float p = __expf(s[ct][r] - m[r]);
        s[ct][r] = p;                         // reuse s as P
        rs += p;
      }
#pragma unroll
      for (int off = 8; off >= 1; off >>= 1) rs += __shfl_xor(rs, off);
      l[r] = l[r] * sc_f[r] + rs;
#pragma unroll
      for (int dt = 0; dt < 4; ++dt) o[dt][r] *= sc_f[r];
    }

    // ---- P -> per-wave LDS (A-frag layout source), swizzled cols
#pragma unroll
    for (int ct = 0; ct < 4; ++ct)
#pragma unroll
      for (int r = 0; r < 4; ++r) {
        const int q = (seg << 2) + r;
        const int colp = ((ct << 4) + lq) ^ ((q & 7) << 3);
        Ps[wid][q][colp] = (bf16)s[ct][r];
      }

    // ---- PV: O += P[16][64] @ V[64][64]
#pragma unroll
    for (int ks = 0; ks < 2; ++ks) {
      const int blkp = ((ks << 2) + seg) ^ (lq & 7);
      const bf16x8 af = *(const bf16x8*)(&Ps[wid][lq][blkp << 3]);
#pragma unroll
      for (int dt = 0; dt < 4; ++dt) {
        const int xv = (lq & 7) ^ (((dt << 1) + (lq >> 3)) & 7);
        const int blkv = ((ks << 2) + seg) ^ xv;
        const bf16x8 bv = *(const bf16x8*)(&Vt[(dt << 4) + lq][blkv << 3]);
        o[dt] = __builtin_amdgcn_mfma_f32_16x16x32_bf16(af, bv, o[dt], 0, 0, 0);
      }
    }
  }

  // ---- epilogue: normalize and store
  float rinv[4];
#pragma unroll
  for (int r = 0; r < 4; ++r) rinv[r] = 1.f / l[r];
#pragma unroll
  for (int dt = 0; dt < 4; ++dt)
#pragma unroll
    for (int r = 0; r < 4; ++r) {
      const int qrow = (qb << 6) + (wid << 4) + (seg << 2) + r;
      out[(size_t)qrow * DM + h * HD + (dt << 4) + lq] = (bf16)(o[dt][r] * rinv[r]);
    }
}

// ---------------------------------------------------------------------------
extern "C" void kernel_launch(void* const* d_in, const int* in_sizes, int n_in,
                              void* d_out, int out_size, void* d_ws, size_t ws_size,
                              hipStream_t stream) {
  (void)in_sizes; (void)n_in; (void)out_size; (void)ws_size;
  const float* hidden = (const float*)d_in[0];
  const float* w_qkv  = (const float*)d_in[1];
  const float* b_qkv  = (const float*)d_in[2];
  const float* w_out  = (const float*)d_in[3];
  const float* b_out  = (const float*)d_in[4];
  float* out = (float*)d_out;

  bf16* qkvbuf  = (bf16*)d_ws;                          // [2048][6144] bf16
  bf16* attnbuf = qkvbuf + (size_t)S_LEN * (3 * DM);    // [2048][2048] bf16

  dim3 blk(256);
  // QKV projection: M=2048, N=6144, K=2048
  gemm_bias_bt<float, float, bf16><<<dim3(48, 16), blk, 0, stream>>>(
      hidden, w_qkv, b_qkv, qkvbuf, S_LEN, 3 * DM, DM);
  // Flash causal attention per (64-query tile, head)
  attn_flash<<<dim3(32, NH), blk, 0, stream>>>(qkvbuf, attnbuf);
  // Output projection: M=2048, N=2048, K=2048
  gemm_bias_bt<bf16, float, float><<<dim3(16, 16), blk, 0, stream>>>(
      attnbuf, w_out, b_out, out, S_LEN, DM, DM);
}

// Round 4
// 260.216 us; speedup vs baseline: 3.4275x; 1.0597x over previous
//
#include <hip/hip_runtime.h>
#include <hip/hip_bf16.h>

typedef __bf16 bf16;
typedef __attribute__((ext_vector_type(8))) __bf16 bf16x8;
typedef __attribute__((ext_vector_type(4))) float f32x4;

#define S_LEN 2048
#define DM 2048
#define NH 32
#define HD 64
#define QKV_LD 6144
#define SCALE_F 0.125f

// Async global->LDS, 16B per lane. LDS dest must be wave-uniform base; data
// lands at base + lane*16. AS casts via uintptr_t round-trip (generic LDS
// pointer's low 32 bits == LDS byte offset on amdgcn).
__device__ __forceinline__ void gload_lds16(const bf16* g, const bf16* l) {
  __builtin_amdgcn_global_load_lds(
      (const __attribute__((address_space(1))) void*)(uintptr_t)g,
      (__attribute__((address_space(3))) void*)(uint32_t)(uintptr_t)l,
      16, 0, 0);
}

// ---------------------------------------------------------------------------
// f32 -> bf16 conversion (vectorized, memory-bound)
// ---------------------------------------------------------------------------
__global__ __launch_bounds__(256) void cvt_f32_bf16(
    const float* __restrict__ src, bf16* __restrict__ dst, const int n8)
{
  const int i = blockIdx.x * blockDim.x + threadIdx.x;
  if (i >= n8) return;
  const f32x4 a = *(const f32x4*)(src + (size_t)i * 8);
  const f32x4 b = *(const f32x4*)(src + (size_t)i * 8 + 4);
  bf16x8 r;
  r[0] = (bf16)a[0]; r[1] = (bf16)a[1]; r[2] = (bf16)a[2]; r[3] = (bf16)a[3];
  r[4] = (bf16)b[0]; r[5] = (bf16)b[1]; r[6] = (bf16)b[2]; r[7] = (bf16)b[3];
  *(bf16x8*)(dst + (size_t)i * 8) = r;
}

// ---------------------------------------------------------------------------
// GEMM: C[M][N] = A[M][K] @ W[N][K]^T + bias[N]   (bf16 operands, f32 accum)
// m97 structure: 128x128 tile, BK=32, 4 waves, global_load_lds width-16
// staging into linear LDS, 2 barriers per K-step, 16 MFMA per K-step/wave.
// ---------------------------------------------------------------------------
template <typename TO>
__global__ __launch_bounds__(256) void gemm_bt_bf16(
    const bf16* __restrict__ A, const bf16* __restrict__ W,
    const float* __restrict__ bias, TO* __restrict__ C,
    const int M, const int N, const int K)
{
  __shared__ __align__(16) bf16 As[128 * 32];
  __shared__ __align__(16) bf16 Bs[128 * 32];
  const int tid  = threadIdx.x;
  const int lane = tid & 63;
  const int wid  = tid >> 6;
  const int wr = wid >> 1, wc = wid & 1;
  const int row0 = blockIdx.y << 7, col0 = blockIdx.x << 7;
  const int lq = lane & 15, seg = lane >> 4;

  const f32x4 fzero = {0.f, 0.f, 0.f, 0.f};
  f32x4 acc[4][4];
#pragma unroll
  for (int i = 0; i < 4; ++i)
#pragma unroll
    for (int j = 0; j < 4; ++j) acc[i][j] = fzero;

  // per-lane global source row/chunk for staging (idx = c*256 + tid)
  const int nk = K >> 5;
  for (int kt = 0; kt < nk; ++kt) {
    const int k0 = kt << 5;
    __syncthreads();   // all waves done reading LDS from previous K-step
#pragma unroll
    for (int c = 0; c < 2; ++c) {
      const int idx = (c << 8) + tid;       // 0..511
      const int r = idx >> 2, ch = idx & 3; // row 0..127, 16B chunk 0..3
      // LDS dest: wave-uniform base (elements); lane data at +lane*8 elems
      const bf16* adst = As + (size_t)((c << 8) + (wid << 6)) * 8;
      const bf16* bdst = Bs + (size_t)((c << 8) + (wid << 6)) * 8;
      gload_lds16(A + (size_t)(row0 + r) * K + (k0 + (ch << 3)), adst);
      gload_lds16(W + (size_t)(col0 + r) * K + (k0 + (ch << 3)), bdst);
    }
    __syncthreads();   // drains vmcnt(0) -> tiles ready
    bf16x8 af[4], bfr[4];
#pragma unroll
    for (int i = 0; i < 4; ++i) {
      af[i]  = *(const bf16x8*)(As + ((wr << 6) + (i << 4) + lq) * 32 + seg * 8);
      bfr[i] = *(const bf16x8*)(Bs + ((wc << 6) + (i << 4) + lq) * 32 + seg * 8);
    }
#pragma unroll
    for (int i = 0; i < 4; ++i)
#pragma unroll
      for (int j = 0; j < 4; ++j)
        acc[i][j] = __builtin_amdgcn_mfma_f32_16x16x32_bf16(af[i], bfr[j], acc[i][j], 0, 0, 0);
  }

  // Epilogue: C/D layout row=(lane>>4)*4+r, col=lane&15 (m89/m91-verified)
#pragma unroll
  for (int j = 0; j < 4; ++j) {
    const int col = col0 + (wc << 6) + (j << 4) + lq;
    const float bv = bias[col];
#pragma unroll
    for (int i = 0; i < 4; ++i) {
      const int rbase = row0 + (wr << 6) + (i << 4) + (seg << 2);
#pragma unroll
      for (int r = 0; r < 4; ++r)
        C[(size_t)(rbase + r) * N + col] = (TO)(acc[i][j][r] + bv);
    }
  }
}

// ---------------------------------------------------------------------------
// Flash-style causal attention. Block = (64-query tile, head), 4 waves.
// Wave w owns query rows qb*64 + w*16 .. +15. KV tiles of 64 keys staged in
// LDS (K row-major swizzled, V transposed swizzled), online softmax in regs.
// T14 async-stage: next tile's global loads issue before compute.
// ---------------------------------------------------------------------------
__global__ __launch_bounds__(256) void attn_flash(
    const bf16* __restrict__ qkv, bf16* __restrict__ out)
{
  __shared__ __align__(16) bf16 Ks[64][64];       // [key][d], col-swizzled
  __shared__ __align__(16) bf16 Vt[64][64];       // [d][key], key-swizzled
  __shared__ __align__(16) bf16 Ps[4][16][64];    // per-wave P, col-swizzled
  const int qb  = (int)gridDim.x - 1 - (int)blockIdx.x;  // big blocks first
  const int h   = blockIdx.y;
  const int tid = threadIdx.x;
  const int lane = tid & 63, wid = tid >> 6;
  const int lq = lane & 15, seg = lane >> 4;

  const bf16* Qg = qkv + (size_t)(qb * 64 + wid * 16) * QKV_LD + h * HD;
  const bf16* Kg = qkv + DM + h * HD;
  const bf16* Vg = qkv + 2 * DM + h * HD;

  // Q A-fragments: row lq of this wave's 16-query slice, k = d
  bf16x8 qf[2];
  qf[0] = *(const bf16x8*)(Qg + (size_t)lq * QKV_LD + seg * 8);
  qf[1] = *(const bf16x8*)(Qg + (size_t)lq * QKV_LD + 32 + seg * 8);

  const f32x4 fz = {0.f, 0.f, 0.f, 0.f};
  f32x4 o[4] = {fz, fz, fz, fz};    // O[q=seg*4+r][d=dt*16+lq]
  float m[4], l[4];
#pragma unroll
  for (int r = 0; r < 4; ++r) { m[r] = -1e30f; l[r] = 0.f; }

  const int srow = tid >> 3, sch = tid & 7;  // staging: row, 8-elem chunk

  // prefetch KV tile 0 into registers
  bf16x8 kr[2], vr[2];
#pragma unroll
  for (int c = 0; c < 2; ++c) {
    const int row = (c << 5) + srow;
    kr[c] = *(const bf16x8*)(Kg + (size_t)row * QKV_LD + (sch << 3));
    vr[c] = *(const bf16x8*)(Vg + (size_t)row * QKV_LD + (sch << 3));
  }

  for (int nt = 0; nt <= qb; ++nt) {
    __syncthreads();   // previous tile's reads complete
    // ---- stage K (swizzled rows) and V (transposed, swizzled keys) from regs
#pragma unroll
    for (int c = 0; c < 2; ++c) {
      const int row = (c << 5) + srow;     // 0..63
      *(bf16x8*)(&Ks[row][(sch ^ (row & 7)) << 3]) = kr[c];
#pragma unroll
      for (int j = 0; j < 8; ++j) {
        const int keyp = row ^ ((j ^ sch) << 3);   // xorv(d)=(d&7)^((d>>3)&7)
        Vt[(sch << 3) + j][keyp] = vr[c][j];
      }
    }
    __syncthreads();   // tiles ready

    // ---- issue next tile's global loads (in flight during compute)
    if (nt < qb) {
#pragma unroll
      for (int c = 0; c < 2; ++c) {
        const int row = ((nt + 1) << 6) + (c << 5) + srow;
        kr[c] = *(const bf16x8*)(Kg + (size_t)row * QKV_LD + (sch << 3));
        vr[c] = *(const bf16x8*)(Vg + (size_t)row * QKV_LD + (sch << 3));
      }
    }

    // ---- QK^T: scores S[q=seg*4+r][key=ct*16+lq]
    f32x4 s[4];
#pragma unroll
    for (int ct = 0; ct < 4; ++ct) {
      s[ct] = fz;
#pragma unroll
      for (int ks = 0; ks < 2; ++ks) {
        const int blk = ((ks << 2) + seg) ^ (lq & 7);
        const bf16x8 kf = *(const bf16x8*)(&Ks[(ct << 4) + lq][blk << 3]);
        s[ct] = __builtin_amdgcn_mfma_f32_16x16x32_bf16(qf[ks], kf, s[ct], 0, 0, 0);
      }
    }

    // ---- scale + causal mask (diagonal tile only)
    const bool diag = (nt == qb);
#pragma unroll
    for (int ct = 0; ct < 4; ++ct) {
      const int key = (nt << 6) + (ct << 4) + lq;
#pragma unroll
      for (int r = 0; r < 4; ++r) {
        float v = s[ct][r] * SCALE_F;
        if (diag) {
          const int qrow = (qb << 6) + (wid << 4) + (seg << 2) + r;
          if (key > qrow) v = -1e30f;
        }
        s[ct][r] = v;
      }
    }

    // ---- online softmax update (row-reduce over lq lanes)
    float sc_f[4];
#pragma unroll
    for (int r = 0; r < 4; ++r) {
      float tm = fmaxf(fmaxf(s[0][r], s[1][r]), fmaxf(s[2][r], s[3][r]));
#pragma unroll
      for (int off = 8; off >= 1; off >>= 1) tm = fmaxf(tm, __shfl_xor(tm, off));
      const float mn = fmaxf(m[r], tm);
      sc_f[r] = __expf(m[r] - mn);
      m[r] = mn;
    }
#pragma unroll
    for (int r = 0; r < 4; ++r) {
      float rs = 0.f;
#pragma unroll
      for (int ct = 0; ct < 4; ++ct) {
        const float p = __expf(s[ct][r] - m[r]);
        s[ct][r] = p;                         // reuse s as P
        rs += p;
      }
#pragma unroll
      for (int off = 8; off >= 1; off >>= 1) rs += __shfl_xor(rs, off);
      l[r] = l[r] * sc_f[r] + rs;
#pragma unroll
      for (int dt = 0; dt < 4; ++dt) o[dt][r] *= sc_f[r];
    }

    // ---- P -> per-wave LDS (A-frag layout source), swizzled cols
#pragma unroll
    for (int ct = 0; ct < 4; ++ct)
#pragma unroll
      for (int r = 0; r < 4; ++r) {
        const int q = (seg << 2) + r;
        const int colp = ((ct << 4) + lq) ^ ((q & 7) << 3);
        Ps[wid][q][colp] = (bf16)s[ct][r];
      }

    // ---- PV: O += P[16][64] @ V[64][64]
#pragma unroll
    for (int ks = 0; ks < 2; ++ks) {
      const int blkp = ((ks << 2) + seg) ^ (lq & 7);
      const bf16x8 af = *(const bf16x8*)(&Ps[wid][lq][blkp << 3]);
#pragma unroll
      for (int dt = 0; dt < 4; ++dt) {
        const int xv = (lq & 7) ^ (((dt << 1) + (lq >> 3)) & 7);
        const int blkv = ((ks << 2) + seg) ^ xv;
        const bf16x8 bv = *(const bf16x8*)(&Vt[(dt << 4) + lq][blkv << 3]);
        o[dt] = __builtin_amdgcn_mfma_f32_16x16x32_bf16(af, bv, o[dt], 0, 0, 0);
      }
    }
  }

  // ---- epilogue: normalize and store
  float rinv[4];
#pragma unroll
  for (int r = 0; r < 4; ++r) rinv[r] = 1.f / l[r];
#pragma unroll
  for (int dt = 0; dt < 4; ++dt)
#pragma unroll
    for (int r = 0; r < 4; ++r) {
      const int qrow = (qb << 6) + (wid << 4) + (seg << 2) + r;
      out[(size_t)qrow * DM + h * HD + (dt << 4) + lq] = (bf16)(o[dt][r] * rinv[r]);
    }
}

// ---------------------------------------------------------------------------
extern "C" void kernel_launch(void* const* d_in, const int* in_sizes, int n_in,
                              void* d_out, int out_size, void* d_ws, size_t ws_size,
                              hipStream_t stream) {
  (void)in_sizes; (void)n_in; (void)out_size; (void)ws_size;
  const float* hidden = (const float*)d_in[0];
  const float* w_qkv  = (const float*)d_in[1];
  const float* b_qkv  = (const float*)d_in[2];
  const float* w_out  = (const float*)d_in[3];
  const float* b_out  = (const float*)d_in[4];
  float* out = (float*)d_out;

  bf16* qkvbuf  = (bf16*)d_ws;                            // [2048][6144]
  bf16* attnbuf = qkvbuf  + (size_t)S_LEN * (3 * DM);     // [2048][2048]
  bf16* hidb    = attnbuf + (size_t)S_LEN * DM;           // [2048][2048]
  bf16* wqkvb   = hidb    + (size_t)S_LEN * DM;           // [6144][2048]
  bf16* woutb   = wqkvb   + (size_t)(3 * DM) * DM;        // [2048][2048]

  dim3 blk(256);
  // f32 -> bf16 conversions
  cvt_f32_bf16<<<dim3(2048), blk, 0, stream>>>(hidden, hidb, (S_LEN * DM) / 8);
  cvt_f32_bf16<<<dim3(6144), blk, 0, stream>>>(w_qkv, wqkvb, (3 * DM * DM) / 8);
  cvt_f32_bf16<<<dim3(2048), blk, 0, stream>>>(w_out, woutb, (DM * DM) / 8);
  // QKV projection: M=2048, N=6144, K=2048
  gemm_bt_bf16<bf16><<<dim3(48, 16), blk, 0, stream>>>(
      hidb, wqkvb, b_qkv, qkvbuf, S_LEN, 3 * DM, DM);
  // Flash causal attention per (64-query tile, head)
  attn_flash<<<dim3(32, NH), blk, 0, stream>>>(qkvbuf, attnbuf);
  // Output projection: M=2048, N=2048, K=2048
  gemm_bt_bf16<float><<<dim3(16, 16), blk, 0, stream>>>(
      attnbuf, woutb, b_out, out, S_LEN, DM, DM);
}

// Round 5
// 230.590 us; speedup vs baseline: 3.8679x; 1.1285x over previous
//
#include <hip/hip_runtime.h>
#include <hip/hip_bf16.h>

typedef __bf16 bf16;
typedef __attribute__((ext_vector_type(8))) __bf16 bf16x8;
typedef __attribute__((ext_vector_type(4))) float f32x4;

#define S_LEN 2048
#define DM 2048
#define NH 32
#define HD 64
#define QKV_LD 6144
#define SCALE_F 0.125f

// Async global->LDS, 16B per lane. LDS dest must be wave-uniform base; data
// lands at base + lane*16.
__device__ __forceinline__ void gload_lds16(const bf16* g, const bf16* l) {
  __builtin_amdgcn_global_load_lds(
      (const __attribute__((address_space(1))) void*)(uintptr_t)g,
      (__attribute__((address_space(3))) void*)(uint32_t)(uintptr_t)l,
      16, 0, 0);
}

// DPP cross-lane move (VALU pipe — no LDS latency).
template <int CTRL>
__device__ __forceinline__ float fdpp(float x) {
  return __builtin_bit_cast(float,
      __builtin_amdgcn_update_dpp(0, __builtin_bit_cast(int, x), CTRL, 0xF, 0xF, true));
}
// Exact 16-lane butterfly all-reduce: masks {1,2,7,15} are GF(2)-independent.
__device__ __forceinline__ float red16_max(float x) {
  x = fmaxf(x, fdpp<0xB1>(x));    // quad_perm [1,0,3,2]  : xor 1
  x = fmaxf(x, fdpp<0x4E>(x));    // quad_perm [2,3,0,1]  : xor 2
  x = fmaxf(x, fdpp<0x141>(x));   // row_half_mirror      : xor 7
  x = fmaxf(x, fdpp<0x140>(x));   // row_mirror           : xor 15
  return x;
}
__device__ __forceinline__ float red16_sum(float x) {
  x += fdpp<0xB1>(x);
  x += fdpp<0x4E>(x);
  x += fdpp<0x141>(x);
  x += fdpp<0x140>(x);
  return x;
}

// ---------------------------------------------------------------------------
// f32 -> bf16 conversion (vectorized, memory-bound)
// ---------------------------------------------------------------------------
__global__ __launch_bounds__(256) void cvt_f32_bf16(
    const float* __restrict__ src, bf16* __restrict__ dst, const int n8)
{
  const int i = blockIdx.x * blockDim.x + threadIdx.x;
  if (i >= n8) return;
  const f32x4 a = *(const f32x4*)(src + (size_t)i * 8);
  const f32x4 b = *(const f32x4*)(src + (size_t)i * 8 + 4);
  bf16x8 r;
  r[0] = (bf16)a[0]; r[1] = (bf16)a[1]; r[2] = (bf16)a[2]; r[3] = (bf16)a[3];
  r[4] = (bf16)b[0]; r[5] = (bf16)b[1]; r[6] = (bf16)b[2]; r[7] = (bf16)b[3];
  *(bf16x8*)(dst + (size_t)i * 8) = r;
}

// ---------------------------------------------------------------------------
// GEMM: C[M][N] = A[M][K] @ W[N][K]^T + bias[N]   (bf16 operands, f32 accum)
// m97 structure, templated tile: BMxBN, 4 waves arranged WRNxWCN,
// global_load_lds width-16 staging, 2 barriers/K-step.
// ---------------------------------------------------------------------------
template <int BM, int BN, int WRN, int WCN, typename TO>
__global__ __launch_bounds__(256) void gemm_bt(
    const bf16* __restrict__ A, const bf16* __restrict__ W,
    const float* __restrict__ bias, TO* __restrict__ C,
    const int M, const int N, const int K)
{
  constexpr int WM = BM / WRN;          // wave tile rows
  constexpr int WN = BN / WCN;          // wave tile cols
  constexpr int MI = WM / 16;
  constexpr int NI = WN / 16;
  constexpr int CA = (BM * 32) / 2048;  // 16B gload chunks per K-step (A)
  constexpr int CB = (BN * 32) / 2048;  // (B)
  __shared__ __align__(16) bf16 As[BM * 32];
  __shared__ __align__(16) bf16 Bs[BN * 32];
  const int tid  = threadIdx.x;
  const int lane = tid & 63;
  const int wid  = tid >> 6;
  const int wr = wid / WCN, wc = wid % WCN;
  const int row0 = blockIdx.y * BM, col0 = blockIdx.x * BN;
  const int lq = lane & 15, seg = lane >> 4;

  const f32x4 fzero = {0.f, 0.f, 0.f, 0.f};
  f32x4 acc[MI][NI];
#pragma unroll
  for (int i = 0; i < MI; ++i)
#pragma unroll
    for (int j = 0; j < NI; ++j) acc[i][j] = fzero;

  const int nk = K >> 5;
  for (int kt = 0; kt < nk; ++kt) {
    const int k0 = kt << 5;
    __syncthreads();   // all waves done reading LDS from previous K-step
#pragma unroll
    for (int c = 0; c < CA; ++c) {
      const int idx = (c << 8) + tid;       // 0..CA*256-1
      const int r = idx >> 2, ch = idx & 3; // row, 16B chunk
      gload_lds16(A + (size_t)(row0 + r) * K + (k0 + (ch << 3)),
                  As + (size_t)((c << 8) + (wid << 6)) * 8);
    }
#pragma unroll
    for (int c = 0; c < CB; ++c) {
      const int idx = (c << 8) + tid;
      const int r = idx >> 2, ch = idx & 3;
      gload_lds16(W + (size_t)(col0 + r) * K + (k0 + (ch << 3)),
                  Bs + (size_t)((c << 8) + (wid << 6)) * 8);
    }
    __syncthreads();   // drains vmcnt(0) -> tiles ready
    bf16x8 af[MI], bfr[NI];
#pragma unroll
    for (int i = 0; i < MI; ++i)
      af[i]  = *(const bf16x8*)(As + (wr * WM + (i << 4) + lq) * 32 + seg * 8);
#pragma unroll
    for (int j = 0; j < NI; ++j)
      bfr[j] = *(const bf16x8*)(Bs + (wc * WN + (j << 4) + lq) * 32 + seg * 8);
#pragma unroll
    for (int i = 0; i < MI; ++i)
#pragma unroll
      for (int j = 0; j < NI; ++j)
        acc[i][j] = __builtin_amdgcn_mfma_f32_16x16x32_bf16(af[i], bfr[j], acc[i][j], 0, 0, 0);
  }

  // Epilogue: C/D layout row=(lane>>4)*4+r, col=lane&15 (m89/m91-verified)
#pragma unroll
  for (int j = 0; j < NI; ++j) {
    const int col = col0 + wc * WN + (j << 4) + lq;
    const float bv = bias[col];
#pragma unroll
    for (int i = 0; i < MI; ++i) {
      const int rbase = row0 + wr * WM + (i << 4) + (seg << 2);
#pragma unroll
      for (int r = 0; r < 4; ++r)
        C[(size_t)(rbase + r) * N + col] = (TO)(acc[i][j][r] + bv);
    }
  }
}

// ---------------------------------------------------------------------------
// Flash-style causal attention. Block = (64-query tile, head), 4 waves.
// KV tiles of 64 keys staged in LDS (K swizzled, V transposed swizzled),
// online softmax in regs with DPP butterfly reduce, T14 reg-prefetch.
// ---------------------------------------------------------------------------
__global__ __launch_bounds__(256) void attn_flash(
    const bf16* __restrict__ qkv, bf16* __restrict__ out)
{
  __shared__ __align__(16) bf16 Ks[64][64];       // [key][d], col-swizzled
  __shared__ __align__(16) bf16 Vt[64][64];       // [d][key], key-swizzled
  __shared__ __align__(16) bf16 Ps[4][16][64];    // per-wave P, col-swizzled
  const int qb  = (int)gridDim.x - 1 - (int)blockIdx.x;  // big blocks first
  const int h   = blockIdx.y;
  const int tid = threadIdx.x;
  const int lane = tid & 63, wid = tid >> 6;
  const int lq = lane & 15, seg = lane >> 4;

  const bf16* Qg = qkv + (size_t)(qb * 64 + wid * 16) * QKV_LD + h * HD;
  const bf16* Kg = qkv + DM + h * HD;
  const bf16* Vg = qkv + 2 * DM + h * HD;

  bf16x8 qf[2];
  qf[0] = *(const bf16x8*)(Qg + (size_t)lq * QKV_LD + seg * 8);
  qf[1] = *(const bf16x8*)(Qg + (size_t)lq * QKV_LD + 32 + seg * 8);

  const f32x4 fz = {0.f, 0.f, 0.f, 0.f};
  f32x4 o[4] = {fz, fz, fz, fz};    // O[q=seg*4+r][d=dt*16+lq]
  float m[4], l[4];
#pragma unroll
  for (int r = 0; r < 4; ++r) { m[r] = -1e30f; l[r] = 0.f; }

  const int srow = tid >> 3, sch = tid & 7;  // staging: row, 8-elem chunk

  // prefetch KV tile 0 into registers
  bf16x8 kr[2], vr[2];
#pragma unroll
  for (int c = 0; c < 2; ++c) {
    const int row = (c << 5) + srow;
    kr[c] = *(const bf16x8*)(Kg + (size_t)row * QKV_LD + (sch << 3));
    vr[c] = *(const bf16x8*)(Vg + (size_t)row * QKV_LD + (sch << 3));
  }

  for (int nt = 0; nt <= qb; ++nt) {
    __syncthreads();   // previous tile's reads complete
    // ---- stage K (swizzled rows) and V (transposed, swizzled keys) from regs
#pragma unroll
    for (int c = 0; c < 2; ++c) {
      const int row = (c << 5) + srow;     // 0..63
      *(bf16x8*)(&Ks[row][(sch ^ (row & 7)) << 3]) = kr[c];
#pragma unroll
      for (int j = 0; j < 8; ++j) {
        const int keyp = row ^ ((j ^ sch) << 3);   // xorv(d)=(d&7)^((d>>3)&7)
        Vt[(sch << 3) + j][keyp] = vr[c][j];
      }
    }
    __syncthreads();   // tiles ready

    // ---- issue next tile's global loads (in flight during compute)
    if (nt < qb) {
#pragma unroll
      for (int c = 0; c < 2; ++c) {
        const int row = ((nt + 1) << 6) + (c << 5) + srow;
        kr[c] = *(const bf16x8*)(Kg + (size_t)row * QKV_LD + (sch << 3));
        vr[c] = *(const bf16x8*)(Vg + (size_t)row * QKV_LD + (sch << 3));
      }
    }

    // ---- QK^T: scores S[q=seg*4+r][key=ct*16+lq]
    f32x4 s[4];
    __builtin_amdgcn_s_setprio(1);
#pragma unroll
    for (int ct = 0; ct < 4; ++ct) {
      s[ct] = fz;
#pragma unroll
      for (int ks = 0; ks < 2; ++ks) {
        const int blk = ((ks << 2) + seg) ^ (lq & 7);
        const bf16x8 kf = *(const bf16x8*)(&Ks[(ct << 4) + lq][blk << 3]);
        s[ct] = __builtin_amdgcn_mfma_f32_16x16x32_bf16(qf[ks], kf, s[ct], 0, 0, 0);
      }
    }
    __builtin_amdgcn_s_setprio(0);

    // ---- scale + causal mask (diagonal tile only)
    const bool diag = (nt == qb);
#pragma unroll
    for (int ct = 0; ct < 4; ++ct) {
      const int key = (nt << 6) + (ct << 4) + lq;
#pragma unroll
      for (int r = 0; r < 4; ++r) {
        float v = s[ct][r] * SCALE_F;
        if (diag) {
          const int qrow = (qb << 6) + (wid << 4) + (seg << 2) + r;
          if (key > qrow) v = -1e30f;
        }
        s[ct][r] = v;
      }
    }

    // ---- online softmax update (DPP butterfly row-reduce over lq lanes)
    float sc_f[4];
#pragma unroll
    for (int r = 0; r < 4; ++r) {
      float tm = fmaxf(fmaxf(s[0][r], s[1][r]), fmaxf(s[2][r], s[3][r]));
      tm = red16_max(tm);
      const float mn = fmaxf(m[r], tm);
      sc_f[r] = __expf(m[r] - mn);
      m[r] = mn;
    }
#pragma unroll
    for (int r = 0; r < 4; ++r) {
      float rs = 0.f;
#pragma unroll
      for (int ct = 0; ct < 4; ++ct) {
        const float p = __expf(s[ct][r] - m[r]);
        s[ct][r] = p;                         // reuse s as P
        rs += p;
      }
      rs = red16_sum(rs);
      l[r] = l[r] * sc_f[r] + rs;
#pragma unroll
      for (int dt = 0; dt < 4; ++dt) o[dt][r] *= sc_f[r];
    }

    // ---- P -> per-wave LDS (A-frag layout source), swizzled cols
#pragma unroll
    for (int ct = 0; ct < 4; ++ct)
#pragma unroll
      for (int r = 0; r < 4; ++r) {
        const int q = (seg << 2) + r;
        const int colp = ((ct << 4) + lq) ^ ((q & 7) << 3);
        Ps[wid][q][colp] = (bf16)s[ct][r];
      }

    // ---- PV: O += P[16][64] @ V[64][64]
    __builtin_amdgcn_s_setprio(1);
#pragma unroll
    for (int ks = 0; ks < 2; ++ks) {
      const int blkp = ((ks << 2) + seg) ^ (lq & 7);
      const bf16x8 af = *(const bf16x8*)(&Ps[wid][lq][blkp << 3]);
#pragma unroll
      for (int dt = 0; dt < 4; ++dt) {
        const int xv = (lq & 7) ^ (((dt << 1) + (lq >> 3)) & 7);
        const int blkv = ((ks << 2) + seg) ^ xv;
        const bf16x8 bv = *(const bf16x8*)(&Vt[(dt << 4) + lq][blkv << 3]);
        o[dt] = __builtin_amdgcn_mfma_f32_16x16x32_bf16(af, bv, o[dt], 0, 0, 0);
      }
    }
    __builtin_amdgcn_s_setprio(0);
  }

  // ---- epilogue: normalize and store
  float rinv[4];
#pragma unroll
  for (int r = 0; r < 4; ++r) rinv[r] = 1.f / l[r];
#pragma unroll
  for (int dt = 0; dt < 4; ++dt)
#pragma unroll
    for (int r = 0; r < 4; ++r) {
      const int qrow = (qb << 6) + (wid << 4) + (seg << 2) + r;
      out[(size_t)qrow * DM + h * HD + (dt << 4) + lq] = (bf16)(o[dt][r] * rinv[r]);
    }
}

// ---------------------------------------------------------------------------
extern "C" void kernel_launch(void* const* d_in, const int* in_sizes, int n_in,
                              void* d_out, int out_size, void* d_ws, size_t ws_size,
                              hipStream_t stream) {
  (void)in_sizes; (void)n_in; (void)out_size; (void)ws_size;
  const float* hidden = (const float*)d_in[0];
  const float* w_qkv  = (const float*)d_in[1];
  const float* b_qkv  = (const float*)d_in[2];
  const float* w_out  = (const float*)d_in[3];
  const float* b_out  = (const float*)d_in[4];
  float* out = (float*)d_out;

  bf16* qkvbuf  = (bf16*)d_ws;                            // [2048][6144]
  bf16* attnbuf = qkvbuf  + (size_t)S_LEN * (3 * DM);     // [2048][2048]
  bf16* hidb    = attnbuf + (size_t)S_LEN * DM;           // [2048][2048]
  bf16* wqkvb   = hidb    + (size_t)S_LEN * DM;           // [6144][2048]
  bf16* woutb   = wqkvb   + (size_t)(3 * DM) * DM;        // [2048][2048]

  dim3 blk(256);
  // f32 -> bf16 conversions
  cvt_f32_bf16<<<dim3(2048), blk, 0, stream>>>(hidden, hidb, (S_LEN * DM) / 8);
  cvt_f32_bf16<<<dim3(6144), blk, 0, stream>>>(w_qkv, wqkvb, (3 * DM * DM) / 8);
  cvt_f32_bf16<<<dim3(2048), blk, 0, stream>>>(w_out, woutb, (DM * DM) / 8);
  // QKV projection: M=2048, N=6144, K=2048 (128x128 tiles, 3 blocks/CU)
  gemm_bt<128, 128, 2, 2, bf16><<<dim3(48, 16), blk, 0, stream>>>(
      hidb, wqkvb, b_qkv, qkvbuf, S_LEN, 3 * DM, DM);
  // Flash causal attention per (64-query tile, head)
  attn_flash<<<dim3(32, NH), blk, 0, stream>>>(qkvbuf, attnbuf);
  // Output projection: M=2048, N=2048, K=2048 (64x128 tiles -> 512 blocks)
  gemm_bt<64, 128, 1, 4, float><<<dim3(16, 32), blk, 0, stream>>>(
      attnbuf, woutb, b_out, out, S_LEN, DM, DM);
}

// Round 6
// 199.709 us; speedup vs baseline: 4.4660x; 1.1546x over previous
//
#include <hip/hip_runtime.h>
#include <hip/hip_bf16.h>

typedef __bf16 bf16;
typedef __attribute__((ext_vector_type(8))) __bf16 bf16x8;
typedef __attribute__((ext_vector_type(4))) float f32x4;

#define S_LEN 2048
#define DM 2048
#define NH 32
#define HD 64
#define QKV_LD 6144
#define SCALE_F 0.125f

// Async global->LDS, 16B per lane. LDS dest must be wave-uniform base; data
// lands at base + lane*16.
__device__ __forceinline__ void gload_lds16(const bf16* g, const bf16* l) {
  __builtin_amdgcn_global_load_lds(
      (const __attribute__((address_space(1))) void*)(uintptr_t)g,
      (__attribute__((address_space(3))) void*)(uint32_t)(uintptr_t)l,
      16, 0, 0);
}

// DPP cross-lane move (VALU pipe — no LDS latency).
template <int CTRL>
__device__ __forceinline__ float fdpp(float x) {
  return __builtin_bit_cast(float,
      __builtin_amdgcn_update_dpp(0, __builtin_bit_cast(int, x), CTRL, 0xF, 0xF, true));
}
// Exact 16-lane butterfly all-reduce: masks {1,2,7,15} are GF(2)-independent.
__device__ __forceinline__ float red16_max(float x) {
  x = fmaxf(x, fdpp<0xB1>(x));    // quad_perm [1,0,3,2]  : xor 1
  x = fmaxf(x, fdpp<0x4E>(x));    // quad_perm [2,3,0,1]  : xor 2
  x = fmaxf(x, fdpp<0x141>(x));   // row_half_mirror      : xor 7
  x = fmaxf(x, fdpp<0x140>(x));   // row_mirror           : xor 15
  return x;
}
__device__ __forceinline__ float red16_sum(float x) {
  x += fdpp<0xB1>(x);
  x += fdpp<0x4E>(x);
  x += fdpp<0x141>(x);
  x += fdpp<0x140>(x);
  return x;
}

// ---------------------------------------------------------------------------
// f32 -> bf16 conversion (vectorized, memory-bound)
// ---------------------------------------------------------------------------
__global__ __launch_bounds__(256) void cvt_f32_bf16(
    const float* __restrict__ src, bf16* __restrict__ dst, const int n8)
{
  const int i = blockIdx.x * blockDim.x + threadIdx.x;
  if (i >= n8) return;
  const f32x4 a = *(const f32x4*)(src + (size_t)i * 8);
  const f32x4 b = *(const f32x4*)(src + (size_t)i * 8 + 4);
  bf16x8 r;
  r[0] = (bf16)a[0]; r[1] = (bf16)a[1]; r[2] = (bf16)a[2]; r[3] = (bf16)a[3];
  r[4] = (bf16)b[0]; r[5] = (bf16)b[1]; r[6] = (bf16)b[2]; r[7] = (bf16)b[3];
  *(bf16x8*)(dst + (size_t)i * 8) = r;
}

// ---------------------------------------------------------------------------
// GEMM: C[M][N] = A[M][K] @ W[N][K]^T + bias[N]   (bf16 operands, f32 accum)
// m97 structure, templated tile: BMxBN, 4 waves arranged WRNxWCN,
// global_load_lds width-16 staging, 2 barriers/K-step.
// ---------------------------------------------------------------------------
template <int BM, int BN, int WRN, int WCN, typename TO>
__global__ __launch_bounds__(256) void gemm_bt(
    const bf16* __restrict__ A, const bf16* __restrict__ W,
    const float* __restrict__ bias, TO* __restrict__ C,
    const int M, const int N, const int K)
{
  constexpr int WM = BM / WRN;          // wave tile rows
  constexpr int WN = BN / WCN;          // wave tile cols
  constexpr int MI = WM / 16;
  constexpr int NI = WN / 16;
  constexpr int CA = (BM * 32) / 2048;  // 16B gload chunks per K-step (A)
  constexpr int CB = (BN * 32) / 2048;  // (B)
  __shared__ __align__(16) bf16 As[BM * 32];
  __shared__ __align__(16) bf16 Bs[BN * 32];
  const int tid  = threadIdx.x;
  const int lane = tid & 63;
  const int wid  = tid >> 6;
  const int wr = wid / WCN, wc = wid % WCN;
  const int row0 = blockIdx.y * BM, col0 = blockIdx.x * BN;
  const int lq = lane & 15, seg = lane >> 4;

  const f32x4 fzero = {0.f, 0.f, 0.f, 0.f};
  f32x4 acc[MI][NI];
#pragma unroll
  for (int i = 0; i < MI; ++i)
#pragma unroll
    for (int j = 0; j < NI; ++j) acc[i][j] = fzero;

  const int nk = K >> 5;
  for (int kt = 0; kt < nk; ++kt) {
    const int k0 = kt << 5;
    __syncthreads();   // all waves done reading LDS from previous K-step
#pragma unroll
    for (int c = 0; c < CA; ++c) {
      const int idx = (c << 8) + tid;       // 0..CA*256-1
      const int r = idx >> 2, ch = idx & 3; // row, 16B chunk
      gload_lds16(A + (size_t)(row0 + r) * K + (k0 + (ch << 3)),
                  As + (size_t)((c << 8) + (wid << 6)) * 8);
    }
#pragma unroll
    for (int c = 0; c < CB; ++c) {
      const int idx = (c << 8) + tid;
      const int r = idx >> 2, ch = idx & 3;
      gload_lds16(W + (size_t)(col0 + r) * K + (k0 + (ch << 3)),
                  Bs + (size_t)((c << 8) + (wid << 6)) * 8);
    }
    __syncthreads();   // drains vmcnt(0) -> tiles ready
    bf16x8 af[MI], bfr[NI];
#pragma unroll
    for (int i = 0; i < MI; ++i)
      af[i]  = *(const bf16x8*)(As + (wr * WM + (i << 4) + lq) * 32 + seg * 8);
#pragma unroll
    for (int j = 0; j < NI; ++j)
      bfr[j] = *(const bf16x8*)(Bs + (wc * WN + (j << 4) + lq) * 32 + seg * 8);
#pragma unroll
    for (int i = 0; i < MI; ++i)
#pragma unroll
      for (int j = 0; j < NI; ++j)
        acc[i][j] = __builtin_amdgcn_mfma_f32_16x16x32_bf16(af[i], bfr[j], acc[i][j], 0, 0, 0);
  }

  // Epilogue: C/D layout row=(lane>>4)*4+r, col=lane&15 (m89/m91-verified)
#pragma unroll
  for (int j = 0; j < NI; ++j) {
    const int col = col0 + wc * WN + (j << 4) + lq;
    const float bv = bias[col];
#pragma unroll
    for (int i = 0; i < MI; ++i) {
      const int rbase = row0 + wr * WM + (i << 4) + (seg << 2);
#pragma unroll
      for (int r = 0; r < 4; ++r)
        C[(size_t)(rbase + r) * N + col] = (TO)(acc[i][j][r] + bv);
    }
  }
}

// ---------------------------------------------------------------------------
// Per-q-tile flash state (one 16-row slice per wave).
// ---------------------------------------------------------------------------
struct QTile {
  bf16x8 qf[2];
  f32x4  o[4];
  float  m[4], l[4];
};

__device__ __forceinline__ void qtile_init(QTile& st, const bf16* Qg,
                                           const int lq, const int seg) {
  st.qf[0] = *(const bf16x8*)(Qg + (size_t)lq * QKV_LD + seg * 8);
  st.qf[1] = *(const bf16x8*)(Qg + (size_t)lq * QKV_LD + 32 + seg * 8);
  const f32x4 fz = {0.f, 0.f, 0.f, 0.f};
#pragma unroll
  for (int r = 0; r < 4; ++r) { st.o[r] = fz; st.m[r] = -1e30f; st.l[r] = 0.f; }
}

// QK^T -> mask -> online softmax -> P-write -> PV for one staged KV tile.
__device__ __forceinline__ void qtile_step(
    QTile& st, const int qb, const int nt,
    const int wid, const int lq, const int seg,
    const bf16 (&Ks)[64][64], const bf16 (&Vt)[64][64], bf16 (&Psw)[16][64])
{
  const f32x4 fz = {0.f, 0.f, 0.f, 0.f};
  f32x4 s[4];
  __builtin_amdgcn_s_setprio(1);
#pragma unroll
  for (int ct = 0; ct < 4; ++ct) {
    s[ct] = fz;
#pragma unroll
    for (int ks = 0; ks < 2; ++ks) {
      const int blk = ((ks << 2) + seg) ^ (lq & 7);
      const bf16x8 kf = *(const bf16x8*)(&Ks[(ct << 4) + lq][blk << 3]);
      s[ct] = __builtin_amdgcn_mfma_f32_16x16x32_bf16(st.qf[ks], kf, s[ct], 0, 0, 0);
    }
  }
  __builtin_amdgcn_s_setprio(0);

  // scale + causal mask (diagonal tile only)
  const bool diag = (nt == qb);
#pragma unroll
  for (int ct = 0; ct < 4; ++ct) {
    const int key = (nt << 6) + (ct << 4) + lq;
#pragma unroll
    for (int r = 0; r < 4; ++r) {
      float v = s[ct][r] * SCALE_F;
      if (diag) {
        const int qrow = (qb << 6) + (wid << 4) + (seg << 2) + r;
        if (key > qrow) v = -1e30f;
      }
      s[ct][r] = v;
    }
  }

  // online softmax update (DPP butterfly row-reduce over lq lanes)
  float sc_f[4];
#pragma unroll
  for (int r = 0; r < 4; ++r) {
    float tm = fmaxf(fmaxf(s[0][r], s[1][r]), fmaxf(s[2][r], s[3][r]));
    tm = red16_max(tm);
    const float mn = fmaxf(st.m[r], tm);
    sc_f[r] = __expf(st.m[r] - mn);
    st.m[r] = mn;
  }
#pragma unroll
  for (int r = 0; r < 4; ++r) {
    float rs = 0.f;
#pragma unroll
    for (int ct = 0; ct < 4; ++ct) {
      const float p = __expf(s[ct][r] - st.m[r]);
      s[ct][r] = p;                         // reuse s as P
      rs += p;
    }
    rs = red16_sum(rs);
    st.l[r] = st.l[r] * sc_f[r] + rs;
#pragma unroll
    for (int dt = 0; dt < 4; ++dt) st.o[dt][r] *= sc_f[r];
  }

  // P -> per-wave LDS (A-frag layout source), swizzled cols
#pragma unroll
  for (int ct = 0; ct < 4; ++ct)
#pragma unroll
    for (int r = 0; r < 4; ++r) {
      const int q = (seg << 2) + r;
      const int colp = ((ct << 4) + lq) ^ ((q & 7) << 3);
      Psw[q][colp] = (bf16)s[ct][r];
    }

  // PV: O += P[16][64] @ V[64][64]
  __builtin_amdgcn_s_setprio(1);
#pragma unroll
  for (int ks = 0; ks < 2; ++ks) {
    const int blkp = ((ks << 2) + seg) ^ (lq & 7);
    const bf16x8 af = *(const bf16x8*)(&Psw[lq][blkp << 3]);
#pragma unroll
    for (int dt = 0; dt < 4; ++dt) {
      const int xv = (lq & 7) ^ (((dt << 1) + (lq >> 3)) & 7);
      const int blkv = ((ks << 2) + seg) ^ xv;
      const bf16x8 bv = *(const bf16x8*)(&Vt[(dt << 4) + lq][blkv << 3]);
      st.o[dt] = __builtin_amdgcn_mfma_f32_16x16x32_bf16(af, bv, st.o[dt], 0, 0, 0);
    }
  }
  __builtin_amdgcn_s_setprio(0);
}

__device__ __forceinline__ void qtile_store(
    const QTile& st, bf16* __restrict__ out, const int qb, const int h,
    const int wid, const int lq, const int seg)
{
  float rinv[4];
#pragma unroll
  for (int r = 0; r < 4; ++r) rinv[r] = 1.f / st.l[r];
#pragma unroll
  for (int dt = 0; dt < 4; ++dt)
#pragma unroll
    for (int r = 0; r < 4; ++r) {
      const int qrow = (qb << 6) + (wid << 4) + (seg << 2) + r;
      out[(size_t)qrow * DM + h * HD + (dt << 4) + lq] =
          (bf16)(st.o[dt][r] * rinv[r]);
    }
}

// ---------------------------------------------------------------------------
// Flash-style causal attention with wrap-paired query tiles.
// Block i handles q-tiles qbA=i and qbB=31-i of head h: constant MFMA work
// per block (33 tile-works), shared KV staging over the common prefix.
// ---------------------------------------------------------------------------
__global__ __launch_bounds__(256) void attn_flash(
    const bf16* __restrict__ qkv, bf16* __restrict__ out)
{
  __shared__ __align__(16) bf16 Ks[64][64];       // [key][d], col-swizzled
  __shared__ __align__(16) bf16 Vt[64][64];       // [d][key], key-swizzled
  __shared__ __align__(16) bf16 Ps[4][16][64];    // per-wave P, col-swizzled
  const int qbA = blockIdx.x;                     // 0..15 (short range)
  const int qbB = 31 - qbA;                       // 31..16 (long range)
  const int h   = blockIdx.y;
  const int tid = threadIdx.x;
  const int lane = tid & 63, wid = tid >> 6;
  const int lq = lane & 15, seg = lane >> 4;

  const bf16* Kg = qkv + DM + h * HD;
  const bf16* Vg = qkv + 2 * DM + h * HD;

  QTile stA, stB;
  qtile_init(stA, qkv + (size_t)(qbA * 64 + wid * 16) * QKV_LD + h * HD, lq, seg);
  qtile_init(stB, qkv + (size_t)(qbB * 64 + wid * 16) * QKV_LD + h * HD, lq, seg);

  const int srow = tid >> 3, sch = tid & 7;  // staging: row, 8-elem chunk

  // prefetch KV tile 0 into registers
  bf16x8 kr[2], vr[2];
#pragma unroll
  for (int c = 0; c < 2; ++c) {
    const int row = (c << 5) + srow;
    kr[c] = *(const bf16x8*)(Kg + (size_t)row * QKV_LD + (sch << 3));
    vr[c] = *(const bf16x8*)(Vg + (size_t)row * QKV_LD + (sch << 3));
  }

  for (int nt = 0; nt <= qbB; ++nt) {
    __syncthreads();   // previous tile's reads complete
    // ---- stage K (swizzled rows) and V (transposed, swizzled keys) from regs
#pragma unroll
    for (int c = 0; c < 2; ++c) {
      const int row = (c << 5) + srow;     // 0..63
      *(bf16x8*)(&Ks[row][(sch ^ (row & 7)) << 3]) = kr[c];
#pragma unroll
      for (int j = 0; j < 8; ++j) {
        const int keyp = row ^ ((j ^ sch) << 3);   // xorv(d)=(d&7)^((d>>3)&7)
        Vt[(sch << 3) + j][keyp] = vr[c][j];
      }
    }
    __syncthreads();   // tiles ready

    // ---- issue next tile's global loads (in flight during compute)
    if (nt < qbB) {
#pragma unroll
      for (int c = 0; c < 2; ++c) {
        const int row = ((nt + 1) << 6) + (c << 5) + srow;
        kr[c] = *(const bf16x8*)(Kg + (size_t)row * QKV_LD + (sch << 3));
        vr[c] = *(const bf16x8*)(Vg + (size_t)row * QKV_LD + (sch << 3));
      }
    }

    // ---- q-tile B (always active), then q-tile A (common prefix only)
    qtile_step(stB, qbB, nt, wid, lq, seg, Ks, Vt, Ps[wid]);
    if (nt <= qbA)
      qtile_step(stA, qbA, nt, wid, lq, seg, Ks, Vt, Ps[wid]);
  }

  qtile_store(stB, out, qbB, h, wid, lq, seg);
  qtile_store(stA, out, qbA, h, wid, lq, seg);
}

// ---------------------------------------------------------------------------
extern "C" void kernel_launch(void* const* d_in, const int* in_sizes, int n_in,
                              void* d_out, int out_size, void* d_ws, size_t ws_size,
                              hipStream_t stream) {
  (void)in_sizes; (void)n_in; (void)out_size; (void)ws_size;
  const float* hidden = (const float*)d_in[0];
  const float* w_qkv  = (const float*)d_in[1];
  const float* b_qkv  = (const float*)d_in[2];
  const float* w_out  = (const float*)d_in[3];
  const float* b_out  = (const float*)d_in[4];
  float* out = (float*)d_out;

  bf16* qkvbuf  = (bf16*)d_ws;                            // [2048][6144]
  bf16* attnbuf = qkvbuf  + (size_t)S_LEN * (3 * DM);     // [2048][2048]
  bf16* hidb    = attnbuf + (size_t)S_LEN * DM;           // [2048][2048]
  bf16* wqkvb   = hidb    + (size_t)S_LEN * DM;           // [6144][2048]
  bf16* woutb   = wqkvb   + (size_t)(3 * DM) * DM;        // [2048][2048]

  dim3 blk(256);
  // f32 -> bf16 conversions
  cvt_f32_bf16<<<dim3(2048), blk, 0, stream>>>(hidden, hidb, (S_LEN * DM) / 8);
  cvt_f32_bf16<<<dim3(6144), blk, 0, stream>>>(w_qkv, wqkvb, (3 * DM * DM) / 8);
  cvt_f32_bf16<<<dim3(2048), blk, 0, stream>>>(w_out, woutb, (DM * DM) / 8);
  // QKV projection: M=2048, N=6144, K=2048 (128x128 tiles, 3 blocks/CU)
  gemm_bt<128, 128, 2, 2, bf16><<<dim3(48, 16), blk, 0, stream>>>(
      hidb, wqkvb, b_qkv, qkvbuf, S_LEN, 3 * DM, DM);
  // Flash causal attention: paired q-tiles (i, 31-i) per block
  attn_flash<<<dim3(16, NH), blk, 0, stream>>>(qkvbuf, attnbuf);
  // Output projection: M=2048, N=2048, K=2048 (64x128 tiles -> 512 blocks)
  gemm_bt<64, 128, 1, 4, float><<<dim3(16, 32), blk, 0, stream>>>(
      attnbuf, woutb, b_out, out, S_LEN, DM, DM);
}

// Round 7
// 180.627 us; speedup vs baseline: 4.9377x; 1.1056x over previous
//
#include <hip/hip_runtime.h>
#include <hip/hip_bf16.h>

typedef __bf16 bf16;
typedef __attribute__((ext_vector_type(8))) __bf16 bf16x8;
typedef __attribute__((ext_vector_type(4))) float f32x4;

#define S_LEN 2048
#define DM 2048
#define NH 32
#define HD 64
#define QKV_LD 6144
#define SCALE_F 0.125f

// Async global->LDS, 16B per lane. LDS dest must be wave-uniform base; data
// lands at base + lane*16.
__device__ __forceinline__ void gload_lds16(const bf16* g, const bf16* l) {
  __builtin_amdgcn_global_load_lds(
      (const __attribute__((address_space(1))) void*)(uintptr_t)g,
      (__attribute__((address_space(3))) void*)(uint32_t)(uintptr_t)l,
      16, 0, 0);
}

// DPP cross-lane move (VALU pipe — no LDS latency).
template <int CTRL>
__device__ __forceinline__ float fdpp(float x) {
  return __builtin_bit_cast(float,
      __builtin_amdgcn_update_dpp(0, __builtin_bit_cast(int, x), CTRL, 0xF, 0xF, true));
}
// Exact 16-lane butterfly all-reduce: masks {1,2,7,15} are GF(2)-independent.
__device__ __forceinline__ float red16_max(float x) {
  x = fmaxf(x, fdpp<0xB1>(x));    // quad_perm [1,0,3,2]  : xor 1
  x = fmaxf(x, fdpp<0x4E>(x));    // quad_perm [2,3,0,1]  : xor 2
  x = fmaxf(x, fdpp<0x141>(x));   // row_half_mirror      : xor 7
  x = fmaxf(x, fdpp<0x140>(x));   // row_mirror           : xor 15
  return x;
}
__device__ __forceinline__ float red16_sum(float x) {
  x += fdpp<0xB1>(x);
  x += fdpp<0x4E>(x);
  x += fdpp<0x141>(x);
  x += fdpp<0x140>(x);
  return x;
}

// ---------------------------------------------------------------------------
// Fused f32 -> bf16 conversion over three arrays (one launch, grid-stride)
// ---------------------------------------------------------------------------
__global__ __launch_bounds__(256) void cvt3_f32_bf16(
    const float* __restrict__ s0, bf16* __restrict__ d0, const int n0,
    const float* __restrict__ s1, bf16* __restrict__ d1, const int n1,
    const float* __restrict__ s2, bf16* __restrict__ d2, const int n2)
{
  const int total = n0 + n1 + n2;
  const int stride = gridDim.x * blockDim.x;
  for (int i = blockIdx.x * blockDim.x + threadIdx.x; i < total; i += stride) {
    const float* s; bf16* d; int j = i;
    if (j < n0)            { s = s0; d = d0; }
    else if (j - n0 < n1)  { s = s1; d = d1; j -= n0; }
    else                   { s = s2; d = d2; j -= n0 + n1; }
    const f32x4 a = *(const f32x4*)(s + (size_t)j * 8);
    const f32x4 b = *(const f32x4*)(s + (size_t)j * 8 + 4);
    bf16x8 r;
    r[0] = (bf16)a[0]; r[1] = (bf16)a[1]; r[2] = (bf16)a[2]; r[3] = (bf16)a[3];
    r[4] = (bf16)b[0]; r[5] = (bf16)b[1]; r[6] = (bf16)b[2]; r[7] = (bf16)b[3];
    *(bf16x8*)(d + (size_t)j * 8) = r;
  }
}

// ---------------------------------------------------------------------------
// GEMM: C[M][N] = A[M][K] @ W[N][K]^T + bias[N]   (bf16 operands, f32 accum)
// T3 minimum 2-phase: double-buffered LDS, ONE barrier per K-step.
// stage(kt+1 -> buf^1) issues gload_lds; 16 MFMA of buf[cur] run while loads
// fly; __syncthreads() (compiler drains vmcnt(0)) hands buffers over.
// ---------------------------------------------------------------------------
template <int BM, int BN, int WRN, int WCN, typename TO>
__global__ __launch_bounds__(256) void gemm_bt(
    const bf16* __restrict__ A, const bf16* __restrict__ W,
    const float* __restrict__ bias, TO* __restrict__ C,
    const int M, const int N, const int K)
{
  constexpr int WM = BM / WRN;          // wave tile rows
  constexpr int WN = BN / WCN;          // wave tile cols
  constexpr int MI = WM / 16;
  constexpr int NI = WN / 16;
  constexpr int CA = (BM * 32) / 2048;  // 16B gload chunks per K-step (A)
  constexpr int CB = (BN * 32) / 2048;  // (B)
  constexpr int BUF = (BM + BN) * 32;   // elements per double-buffer half
  __shared__ __align__(16) bf16 lds[2 * BUF];
  const int tid  = threadIdx.x;
  const int lane = tid & 63;
  const int wid  = tid >> 6;
  const int wr = wid / WCN, wc = wid % WCN;
  const int row0 = blockIdx.y * BM, col0 = blockIdx.x * BN;
  const int lq = lane & 15, seg = lane >> 4;

  const f32x4 fzero = {0.f, 0.f, 0.f, 0.f};
  f32x4 acc[MI][NI];
#pragma unroll
  for (int i = 0; i < MI; ++i)
#pragma unroll
    for (int j = 0; j < NI; ++j) acc[i][j] = fzero;

  auto stage = [&](const int kt, const int b) {
    const int k0 = kt << 5;
    bf16* Ab = lds + b * BUF;
    bf16* Bb = Ab + BM * 32;
#pragma unroll
    for (int c = 0; c < CA; ++c) {
      const int idx = (c << 8) + tid;       // 0..CA*256-1
      const int r = idx >> 2, ch = idx & 3; // row, 16B chunk
      gload_lds16(A + (size_t)(row0 + r) * K + (k0 + (ch << 3)),
                  Ab + (size_t)((c << 8) + (wid << 6)) * 8);
    }
#pragma unroll
    for (int c = 0; c < CB; ++c) {
      const int idx = (c << 8) + tid;
      const int r = idx >> 2, ch = idx & 3;
      gload_lds16(W + (size_t)(col0 + r) * K + (k0 + (ch << 3)),
                  Bb + (size_t)((c << 8) + (wid << 6)) * 8);
    }
  };

  const int nk = K >> 5;
  stage(0, 0);
  __syncthreads();   // vmcnt(0) drain: buffer 0 ready

  int cur = 0;
  for (int kt = 0; kt < nk; ++kt) {
    if (kt + 1 < nk) stage(kt + 1, cur ^ 1);   // loads fly during MFMA below
    const bf16* Ab = lds + cur * BUF;
    const bf16* Bb = Ab + BM * 32;
    bf16x8 af[MI], bfr[NI];
#pragma unroll
    for (int i = 0; i < MI; ++i)
      af[i]  = *(const bf16x8*)(Ab + (wr * WM + (i << 4) + lq) * 32 + seg * 8);
#pragma unroll
    for (int j = 0; j < NI; ++j)
      bfr[j] = *(const bf16x8*)(Bb + (wc * WN + (j << 4) + lq) * 32 + seg * 8);
#pragma unroll
    for (int i = 0; i < MI; ++i)
#pragma unroll
      for (int j = 0; j < NI; ++j)
        acc[i][j] = __builtin_amdgcn_mfma_f32_16x16x32_bf16(af[i], bfr[j], acc[i][j], 0, 0, 0);
    __syncthreads();   // all reads of buf[cur] done + next buffer landed
    cur ^= 1;
  }

  // Epilogue: C/D layout row=(lane>>4)*4+r, col=lane&15 (m89/m91-verified)
#pragma unroll
  for (int j = 0; j < NI; ++j) {
    const int col = col0 + wc * WN + (j << 4) + lq;
    const float bv = bias[col];
#pragma unroll
    for (int i = 0; i < MI; ++i) {
      const int rbase = row0 + wr * WM + (i << 4) + (seg << 2);
#pragma unroll
      for (int r = 0; r < 4; ++r)
        C[(size_t)(rbase + r) * N + col] = (TO)(acc[i][j][r] + bv);
    }
  }
}

// ---------------------------------------------------------------------------
// Per-q-tile flash state (one 16-row slice per wave).
// ---------------------------------------------------------------------------
struct QTile {
  bf16x8 qf[2];
  f32x4  o[4];
  float  m[4], l[4];
};

__device__ __forceinline__ void qtile_init(QTile& st, const bf16* Qg,
                                           const int lq, const int seg) {
  st.qf[0] = *(const bf16x8*)(Qg + (size_t)lq * QKV_LD + seg * 8);
  st.qf[1] = *(const bf16x8*)(Qg + (size_t)lq * QKV_LD + 32 + seg * 8);
  const f32x4 fz = {0.f, 0.f, 0.f, 0.f};
#pragma unroll
  for (int r = 0; r < 4; ++r) { st.o[r] = fz; st.m[r] = -1e30f; st.l[r] = 0.f; }
}

// QK^T -> mask -> online softmax -> P-write -> PV for one staged KV tile.
__device__ __forceinline__ void qtile_step(
    QTile& st, const int qb, const int nt,
    const int wid, const int lq, const int seg,
    const bf16 (&Ks)[64][64], const bf16 (&Vt)[64][64], bf16 (&Psw)[16][64])
{
  const f32x4 fz = {0.f, 0.f, 0.f, 0.f};
  f32x4 s[4];
  __builtin_amdgcn_s_setprio(1);
#pragma unroll
  for (int ct = 0; ct < 4; ++ct) {
    s[ct] = fz;
#pragma unroll
    for (int ks = 0; ks < 2; ++ks) {
      const int blk = ((ks << 2) + seg) ^ (lq & 7);
      const bf16x8 kf = *(const bf16x8*)(&Ks[(ct << 4) + lq][blk << 3]);
      s[ct] = __builtin_amdgcn_mfma_f32_16x16x32_bf16(st.qf[ks], kf, s[ct], 0, 0, 0);
    }
  }
  __builtin_amdgcn_s_setprio(0);

  // scale + causal mask (diagonal tile only)
  const bool diag = (nt == qb);
#pragma unroll
  for (int ct = 0; ct < 4; ++ct) {
    const int key = (nt << 6) + (ct << 4) + lq;
#pragma unroll
    for (int r = 0; r < 4; ++r) {
      float v = s[ct][r] * SCALE_F;
      if (diag) {
        const int qrow = (qb << 6) + (wid << 4) + (seg << 2) + r;
        if (key > qrow) v = -1e30f;
      }
      s[ct][r] = v;
    }
  }

  // online softmax update (DPP butterfly row-reduce over lq lanes)
  float sc_f[4];
#pragma unroll
  for (int r = 0; r < 4; ++r) {
    float tm = fmaxf(fmaxf(s[0][r], s[1][r]), fmaxf(s[2][r], s[3][r]));
    tm = red16_max(tm);
    const float mn = fmaxf(st.m[r], tm);
    sc_f[r] = __expf(st.m[r] - mn);
    st.m[r] = mn;
  }
#pragma unroll
  for (int r = 0; r < 4; ++r) {
    float rs = 0.f;
#pragma unroll
    for (int ct = 0; ct < 4; ++ct) {
      const float p = __expf(s[ct][r] - st.m[r]);
      s[ct][r] = p;                         // reuse s as P
      rs += p;
    }
    rs = red16_sum(rs);
    st.l[r] = st.l[r] * sc_f[r] + rs;
#pragma unroll
    for (int dt = 0; dt < 4; ++dt) st.o[dt][r] *= sc_f[r];
  }

  // P -> per-wave LDS (A-frag layout source), swizzled cols
#pragma unroll
  for (int ct = 0; ct < 4; ++ct)
#pragma unroll
    for (int r = 0; r < 4; ++r) {
      const int q = (seg << 2) + r;
      const int colp = ((ct << 4) + lq) ^ ((q & 7) << 3);
      Psw[q][colp] = (bf16)s[ct][r];
    }

  // PV: O += P[16][64] @ V[64][64]
  __builtin_amdgcn_s_setprio(1);
#pragma unroll
  for (int ks = 0; ks < 2; ++ks) {
    const int blkp = ((ks << 2) + seg) ^ (lq & 7);
    const bf16x8 af = *(const bf16x8*)(&Psw[lq][blkp << 3]);
#pragma unroll
    for (int dt = 0; dt < 4; ++dt) {
      const int xv = (lq & 7) ^ (((dt << 1) + (lq >> 3)) & 7);
      const int blkv = ((ks << 2) + seg) ^ xv;
      const bf16x8 bv = *(const bf16x8*)(&Vt[(dt << 4) + lq][blkv << 3]);
      st.o[dt] = __builtin_amdgcn_mfma_f32_16x16x32_bf16(af, bv, st.o[dt], 0, 0, 0);
    }
  }
  __builtin_amdgcn_s_setprio(0);
}

__device__ __forceinline__ void qtile_store(
    const QTile& st, bf16* __restrict__ out, const int qb, const int h,
    const int wid, const int lq, const int seg)
{
  float rinv[4];
#pragma unroll
  for (int r = 0; r < 4; ++r) rinv[r] = 1.f / st.l[r];
#pragma unroll
  for (int dt = 0; dt < 4; ++dt)
#pragma unroll
    for (int r = 0; r < 4; ++r) {
      const int qrow = (qb << 6) + (wid << 4) + (seg << 2) + r;
      out[(size_t)qrow * DM + h * HD + (dt << 4) + lq] =
          (bf16)(st.o[dt][r] * rinv[r]);
    }
}

// ---------------------------------------------------------------------------
// Flash-style causal attention with wrap-paired query tiles.
// Block i handles q-tiles qbA=i and qbB=31-i of head h: constant MFMA work
// per block (33 tile-works), shared KV staging over the common prefix.
// ---------------------------------------------------------------------------
__global__ __launch_bounds__(256) void attn_flash(
    const bf16* __restrict__ qkv, bf16* __restrict__ out)
{
  __shared__ __align__(16) bf16 Ks[64][64];       // [key][d], col-swizzled
  __shared__ __align__(16) bf16 Vt[64][64];       // [d][key], key-swizzled
  __shared__ __align__(16) bf16 Ps[4][16][64];    // per-wave P, col-swizzled
  const int qbA = blockIdx.x;                     // 0..15 (short range)
  const int qbB = 31 - qbA;                       // 31..16 (long range)
  const int h   = blockIdx.y;
  const int tid = threadIdx.x;
  const int lane = tid & 63, wid = tid >> 6;
  const int lq = lane & 15, seg = lane >> 4;

  const bf16* Kg = qkv + DM + h * HD;
  const bf16* Vg = qkv + 2 * DM + h * HD;

  QTile stA, stB;
  qtile_init(stA, qkv + (size_t)(qbA * 64 + wid * 16) * QKV_LD + h * HD, lq, seg);
  qtile_init(stB, qkv + (size_t)(qbB * 64 + wid * 16) * QKV_LD + h * HD, lq, seg);

  const int srow = tid >> 3, sch = tid & 7;  // staging: row, 8-elem chunk

  // prefetch KV tile 0 into registers
  bf16x8 kr[2], vr[2];
#pragma unroll
  for (int c = 0; c < 2; ++c) {
    const int row = (c << 5) + srow;
    kr[c] = *(const bf16x8*)(Kg + (size_t)row * QKV_LD + (sch << 3));
    vr[c] = *(const bf16x8*)(Vg + (size_t)row * QKV_LD + (sch << 3));
  }

  for (int nt = 0; nt <= qbB; ++nt) {
    __syncthreads();   // previous tile's reads complete
    // ---- stage K (swizzled rows) and V (transposed, swizzled keys) from regs
#pragma unroll
    for (int c = 0; c < 2; ++c) {
      const int row = (c << 5) + srow;     // 0..63
      *(bf16x8*)(&Ks[row][(sch ^ (row & 7)) << 3]) = kr[c];
#pragma unroll
      for (int j = 0; j < 8; ++j) {
        const int keyp = row ^ ((j ^ sch) << 3);   // xorv(d)=(d&7)^((d>>3)&7)
        Vt[(sch << 3) + j][keyp] = vr[c][j];
      }
    }
    __syncthreads();   // tiles ready

    // ---- issue next tile's global loads (in flight during compute)
    if (nt < qbB) {
#pragma unroll
      for (int c = 0; c < 2; ++c) {
        const int row = ((nt + 1) << 6) + (c << 5) + srow;
        kr[c] = *(const bf16x8*)(Kg + (size_t)row * QKV_LD + (sch << 3));
        vr[c] = *(const bf16x8*)(Vg + (size_t)row * QKV_LD + (sch << 3));
      }
    }

    // ---- q-tile B (always active), then q-tile A (common prefix only)
    qtile_step(stB, qbB, nt, wid, lq, seg, Ks, Vt, Ps[wid]);
    if (nt <= qbA)
      qtile_step(stA, qbA, nt, wid, lq, seg, Ks, Vt, Ps[wid]);
  }

  qtile_store(stB, out, qbB, h, wid, lq, seg);
  qtile_store(stA, out, qbA, h, wid, lq, seg);
}

// ---------------------------------------------------------------------------
extern "C" void kernel_launch(void* const* d_in, const int* in_sizes, int n_in,
                              void* d_out, int out_size, void* d_ws, size_t ws_size,
                              hipStream_t stream) {
  (void)in_sizes; (void)n_in; (void)out_size; (void)ws_size;
  const float* hidden = (const float*)d_in[0];
  const float* w_qkv  = (const float*)d_in[1];
  const float* b_qkv  = (const float*)d_in[2];
  const float* w_out  = (const float*)d_in[3];
  const float* b_out  = (const float*)d_in[4];
  float* out = (float*)d_out;

  bf16* qkvbuf  = (bf16*)d_ws;                            // [2048][6144]
  bf16* attnbuf = qkvbuf  + (size_t)S_LEN * (3 * DM);     // [2048][2048]
  bf16* hidb    = attnbuf + (size_t)S_LEN * DM;           // [2048][2048]
  bf16* wqkvb   = hidb    + (size_t)S_LEN * DM;           // [6144][2048]
  bf16* woutb   = wqkvb   + (size_t)(3 * DM) * DM;        // [2048][2048]

  dim3 blk(256);
  // fused f32 -> bf16 conversions (one launch)
  cvt3_f32_bf16<<<dim3(2048), blk, 0, stream>>>(
      hidden, hidb, (S_LEN * DM) / 8,
      w_qkv, wqkvb, (3 * DM * DM) / 8,
      w_out, woutb, (DM * DM) / 8);
  // QKV projection: M=2048, N=6144, K=2048 (128x128 tiles, dbuf pipeline)
  gemm_bt<128, 128, 2, 2, bf16><<<dim3(48, 16), blk, 0, stream>>>(
      hidb, wqkvb, b_qkv, qkvbuf, S_LEN, 3 * DM, DM);
  // Flash causal attention: paired q-tiles (i, 31-i) per block
  attn_flash<<<dim3(16, NH), blk, 0, stream>>>(qkvbuf, attnbuf);
  // Output projection: M=2048, N=2048, K=2048 (64x128 tiles -> 512 blocks)
  gemm_bt<64, 128, 1, 4, float><<<dim3(16, 32), blk, 0, stream>>>(
      attnbuf, woutb, b_out, out, S_LEN, DM, DM);
}

// Round 9
// 163.648 us; speedup vs baseline: 5.4501x; 1.1038x over previous
//
#include <hip/hip_runtime.h>
#include <hip/hip_bf16.h>

typedef __bf16 bf16;
typedef __attribute__((ext_vector_type(8))) __bf16 bf16x8;
typedef __attribute__((ext_vector_type(4))) float f32x4;

#define S_LEN 2048
#define DM 2048
#define NH 32
#define HD 64
#define QKV_LD 6144
// SCALE * log2(e): QK^T scores land directly in log2 domain
#define SCALE2 0.18033688011112042f
#define DEFER_THR 8.0f

// 2^x via v_exp_f32 (gfx9 v_exp IS base-2 exp) — avoids glibc __exp2f clash.
__device__ __forceinline__ float fast_exp2(float x) {
  return __builtin_amdgcn_exp2f(x);
}

// Async global->LDS, 16B per lane. LDS dest must be wave-uniform base; data
// lands at base + lane*16.
__device__ __forceinline__ void gload_lds16(const bf16* g, const bf16* l) {
  __builtin_amdgcn_global_load_lds(
      (const __attribute__((address_space(1))) void*)(uintptr_t)g,
      (__attribute__((address_space(3))) void*)(uint32_t)(uintptr_t)l,
      16, 0, 0);
}

// DPP cross-lane move (VALU pipe — no LDS latency).
template <int CTRL>
__device__ __forceinline__ float fdpp(float x) {
  return __builtin_bit_cast(float,
      __builtin_amdgcn_update_dpp(0, __builtin_bit_cast(int, x), CTRL, 0xF, 0xF, true));
}
// Exact 16-lane butterfly all-reduce: masks {1,2,7,15} are GF(2)-independent.
__device__ __forceinline__ float red16_max(float x) {
  x = fmaxf(x, fdpp<0xB1>(x));    // quad_perm [1,0,3,2]  : xor 1
  x = fmaxf(x, fdpp<0x4E>(x));    // quad_perm [2,3,0,1]  : xor 2
  x = fmaxf(x, fdpp<0x141>(x));   // row_half_mirror      : xor 7
  x = fmaxf(x, fdpp<0x140>(x));   // row_mirror           : xor 15
  return x;
}
__device__ __forceinline__ float red16_sum(float x) {
  x += fdpp<0xB1>(x);
  x += fdpp<0x4E>(x);
  x += fdpp<0x141>(x);
  x += fdpp<0x140>(x);
  return x;
}

// ---------------------------------------------------------------------------
// Fused f32 -> bf16 conversion over three arrays (one launch, grid-stride)
// ---------------------------------------------------------------------------
__global__ __launch_bounds__(256) void cvt3_f32_bf16(
    const float* __restrict__ s0, bf16* __restrict__ d0, const int n0,
    const float* __restrict__ s1, bf16* __restrict__ d1, const int n1,
    const float* __restrict__ s2, bf16* __restrict__ d2, const int n2)
{
  const int total = n0 + n1 + n2;
  const int stride = gridDim.x * blockDim.x;
  for (int i = blockIdx.x * blockDim.x + threadIdx.x; i < total; i += stride) {
    const float* s; bf16* d; int j = i;
    if (j < n0)            { s = s0; d = d0; }
    else if (j - n0 < n1)  { s = s1; d = d1; j -= n0; }
    else                   { s = s2; d = d2; j -= n0 + n1; }
    const f32x4 a = *(const f32x4*)(s + (size_t)j * 8);
    const f32x4 b = *(const f32x4*)(s + (size_t)j * 8 + 4);
    bf16x8 r;
    r[0] = (bf16)a[0]; r[1] = (bf16)a[1]; r[2] = (bf16)a[2]; r[3] = (bf16)a[3];
    r[4] = (bf16)b[0]; r[5] = (bf16)b[1]; r[6] = (bf16)b[2]; r[7] = (bf16)b[3];
    *(bf16x8*)(d + (size_t)j * 8) = r;
  }
}

// ---------------------------------------------------------------------------
// GEMM: C[M][N] = A[M][K] @ W[N][K]^T + bias[N]   (bf16 operands, f32 accum)
// T3 minimum 2-phase: double-buffered LDS, ONE barrier per K-step.
// ---------------------------------------------------------------------------
template <int BM, int BN, int WRN, int WCN, typename TO>
__global__ __launch_bounds__(256) void gemm_bt(
    const bf16* __restrict__ A, const bf16* __restrict__ W,
    const float* __restrict__ bias, TO* __restrict__ C,
    const int M, const int N, const int K)
{
  constexpr int WM = BM / WRN;
  constexpr int WN = BN / WCN;
  constexpr int MI = WM / 16;
  constexpr int NI = WN / 16;
  constexpr int CA = (BM * 32) / 2048;
  constexpr int CB = (BN * 32) / 2048;
  constexpr int BUF = (BM + BN) * 32;
  __shared__ __align__(16) bf16 lds[2 * BUF];
  const int tid  = threadIdx.x;
  const int lane = tid & 63;
  const int wid  = tid >> 6;
  const int wr = wid / WCN, wc = wid % WCN;
  const int row0 = blockIdx.y * BM, col0 = blockIdx.x * BN;
  const int lq = lane & 15, seg = lane >> 4;

  const f32x4 fzero = {0.f, 0.f, 0.f, 0.f};
  f32x4 acc[MI][NI];
#pragma unroll
  for (int i = 0; i < MI; ++i)
#pragma unroll
    for (int j = 0; j < NI; ++j) acc[i][j] = fzero;

  auto stage = [&](const int kt, const int b) {
    const int k0 = kt << 5;
    bf16* Ab = lds + b * BUF;
    bf16* Bb = Ab + BM * 32;
#pragma unroll
    for (int c = 0; c < CA; ++c) {
      const int idx = (c << 8) + tid;
      const int r = idx >> 2, ch = idx & 3;
      gload_lds16(A + (size_t)(row0 + r) * K + (k0 + (ch << 3)),
                  Ab + (size_t)((c << 8) + (wid << 6)) * 8);
    }
#pragma unroll
    for (int c = 0; c < CB; ++c) {
      const int idx = (c << 8) + tid;
      const int r = idx >> 2, ch = idx & 3;
      gload_lds16(W + (size_t)(col0 + r) * K + (k0 + (ch << 3)),
                  Bb + (size_t)((c << 8) + (wid << 6)) * 8);
    }
  };

  const int nk = K >> 5;
  stage(0, 0);
  __syncthreads();

  int cur = 0;
  for (int kt = 0; kt < nk; ++kt) {
    if (kt + 1 < nk) stage(kt + 1, cur ^ 1);
    const bf16* Ab = lds + cur * BUF;
    const bf16* Bb = Ab + BM * 32;
    bf16x8 af[MI], bfr[NI];
#pragma unroll
    for (int i = 0; i < MI; ++i)
      af[i]  = *(const bf16x8*)(Ab + (wr * WM + (i << 4) + lq) * 32 + seg * 8);
#pragma unroll
    for (int j = 0; j < NI; ++j)
      bfr[j] = *(const bf16x8*)(Bb + (wc * WN + (j << 4) + lq) * 32 + seg * 8);
#pragma unroll
    for (int i = 0; i < MI; ++i)
#pragma unroll
      for (int j = 0; j < NI; ++j)
        acc[i][j] = __builtin_amdgcn_mfma_f32_16x16x32_bf16(af[i], bfr[j], acc[i][j], 0, 0, 0);
    __syncthreads();
    cur ^= 1;
  }

#pragma unroll
  for (int j = 0; j < NI; ++j) {
    const int col = col0 + wc * WN + (j << 4) + lq;
    const float bv = bias[col];
#pragma unroll
    for (int i = 0; i < MI; ++i) {
      const int rbase = row0 + wr * WM + (i << 4) + (seg << 2);
#pragma unroll
      for (int r = 0; r < 4; ++r)
        C[(size_t)(rbase + r) * N + col] = (TO)(acc[i][j][r] + bv);
    }
  }
}

// ---------------------------------------------------------------------------
// Per-q-tile flash state (one 16-row slice per wave).
// ---------------------------------------------------------------------------
struct QTile {
  bf16x8 qf[2];    // pre-scaled by SCALE*log2e
  f32x4  o[4];
  float  m[4], l[4];
};

__device__ __forceinline__ void qtile_init(QTile& st, const bf16* Qg,
                                           const int lq, const int seg) {
  const bf16x8 r0 = *(const bf16x8*)(Qg + (size_t)lq * QKV_LD + seg * 8);
  const bf16x8 r1 = *(const bf16x8*)(Qg + (size_t)lq * QKV_LD + 32 + seg * 8);
#pragma unroll
  for (int j = 0; j < 8; ++j) {
    st.qf[0][j] = (bf16)((float)r0[j] * SCALE2);
    st.qf[1][j] = (bf16)((float)r1[j] * SCALE2);
  }
  const f32x4 fz = {0.f, 0.f, 0.f, 0.f};
#pragma unroll
  for (int r = 0; r < 4; ++r) { st.o[r] = fz; st.m[r] = -1e30f; st.l[r] = 0.f; }
}

// QK^T -> mask -> online softmax (log2 domain, defer-max) -> P -> PV.
__device__ __forceinline__ void qtile_step(
    QTile& st, const int qb, const int nt,
    const int ws, const int lq, const int seg,
    const bf16 (&Ks)[64][64], const bf16 (&Vt)[64][64], bf16 (&Psw)[16][64])
{
  const f32x4 fz = {0.f, 0.f, 0.f, 0.f};
  f32x4 s[4];
  __builtin_amdgcn_s_setprio(1);
#pragma unroll
  for (int ct = 0; ct < 4; ++ct) {
    s[ct] = fz;
#pragma unroll
    for (int ks = 0; ks < 2; ++ks) {
      const int blk = ((ks << 2) + seg) ^ (lq & 7);
      const bf16x8 kf = *(const bf16x8*)(&Ks[(ct << 4) + lq][blk << 3]);
      s[ct] = __builtin_amdgcn_mfma_f32_16x16x32_bf16(st.qf[ks], kf, s[ct], 0, 0, 0);
    }
  }
  __builtin_amdgcn_s_setprio(0);

  // causal mask (diagonal tile only); scores already scaled via Q
  if (nt == qb) {
#pragma unroll
    for (int ct = 0; ct < 4; ++ct) {
      const int key = (nt << 6) + (ct << 4) + lq;
#pragma unroll
      for (int r = 0; r < 4; ++r) {
        const int qrow = (qb << 6) + (ws << 4) + (seg << 2) + r;
        if (key > qrow) s[ct][r] = -1e30f;
      }
    }
  }

  // online softmax, log2 domain, defer-max (skip rescale within THR)
#pragma unroll
  for (int r = 0; r < 4; ++r) {
    float tm = fmaxf(fmaxf(s[0][r], s[1][r]), fmaxf(s[2][r], s[3][r]));
    tm = red16_max(tm);
    if (tm > st.m[r] + DEFER_THR) {      // rescale path (rare)
      const float sc = fast_exp2(st.m[r] - tm);
      st.m[r] = tm;
      st.l[r] *= sc;
#pragma unroll
      for (int dt = 0; dt < 4; ++dt) st.o[dt][r] *= sc;
    }
    float rs = 0.f;
#pragma unroll
    for (int ct = 0; ct < 4; ++ct) {
      const float p = fast_exp2(s[ct][r] - st.m[r]);   // bounded by 2^THR
      s[ct][r] = p;
      rs += p;
    }
    rs = red16_sum(rs);
    st.l[r] += rs;
  }

  // P -> per-wave LDS (A-frag layout source), swizzled cols
#pragma unroll
  for (int ct = 0; ct < 4; ++ct)
#pragma unroll
    for (int r = 0; r < 4; ++r) {
      const int q = (seg << 2) + r;
      const int colp = ((ct << 4) + lq) ^ ((q & 7) << 3);
      Psw[q][colp] = (bf16)s[ct][r];
    }

  // PV: O += P[16][64] @ V[64][64]
  __builtin_amdgcn_s_setprio(1);
#pragma unroll
  for (int ks = 0; ks < 2; ++ks) {
    const int blkp = ((ks << 2) + seg) ^ (lq & 7);
    const bf16x8 af = *(const bf16x8*)(&Psw[lq][blkp << 3]);
#pragma unroll
    for (int dt = 0; dt < 4; ++dt) {
      const int xv = (lq & 7) ^ (((dt << 1) + (lq >> 3)) & 7);
      const int blkv = ((ks << 2) + seg) ^ xv;
      const bf16x8 bv = *(const bf16x8*)(&Vt[(dt << 4) + lq][blkv << 3]);
      st.o[dt] = __builtin_amdgcn_mfma_f32_16x16x32_bf16(af, bv, st.o[dt], 0, 0, 0);
    }
  }
  __builtin_amdgcn_s_setprio(0);
}

__device__ __forceinline__ void qtile_store(
    const QTile& st, bf16* __restrict__ out, const int qb, const int h,
    const int ws, const int lq, const int seg)
{
  float rinv[4];
#pragma unroll
  for (int r = 0; r < 4; ++r) rinv[r] = 1.f / st.l[r];
#pragma unroll
  for (int dt = 0; dt < 4; ++dt)
#pragma unroll
    for (int r = 0; r < 4; ++r) {
      const int qrow = (qb << 6) + (ws << 4) + (seg << 2) + r;
      out[(size_t)qrow * DM + h * HD + (dt << 4) + lq] =
          (bf16)(st.o[dt][r] * rinv[r]);
    }
}

// ---------------------------------------------------------------------------
// Flash-style causal attention, 8-wave blocks with wrap-paired q-tiles.
// Waves 0-3 own the four 16-row slices of q-tile qbA=i; waves 4-7 own
// q-tile qbB=31-i. Shared KV staging; 16 waves/CU resident (2 blocks/CU).
// ---------------------------------------------------------------------------
__global__ __launch_bounds__(512) void attn_flash(
    const bf16* __restrict__ qkv, bf16* __restrict__ out)
{
  __shared__ __align__(16) bf16 Ks[64][64];       // [key][d], col-swizzled
  __shared__ __align__(16) bf16 Vt[64][64];       // [d][key], key-swizzled
  __shared__ __align__(16) bf16 Ps[8][16][64];    // per-wave P, col-swizzled
  const int qbA = blockIdx.x;                     // 0..15 (short range)
  const int qbB = 31 - qbA;                       // 31..16 (long range)
  const int h   = blockIdx.y;
  const int tid = threadIdx.x;
  const int lane = tid & 63, wid = tid >> 6;      // wid 0..7
  const int lq = lane & 15, seg = lane >> 4;
  const int myqb = (wid < 4) ? qbA : qbB;
  const int ws   = wid & 3;                       // 16-row slice within tile

  const bf16* Kg = qkv + DM + h * HD;
  const bf16* Vg = qkv + 2 * DM + h * HD;

  QTile st;
  qtile_init(st, qkv + (size_t)(myqb * 64 + ws * 16) * QKV_LD + h * HD, lq, seg);

  const int srow = tid >> 3, sch = tid & 7;  // staging: row 0..63, chunk 0..7

  // prefetch KV tile 0 into registers
  bf16x8 kr = *(const bf16x8*)(Kg + (size_t)srow * QKV_LD + (sch << 3));
  bf16x8 vr = *(const bf16x8*)(Vg + (size_t)srow * QKV_LD + (sch << 3));

  for (int nt = 0; nt <= qbB; ++nt) {
    __syncthreads();   // previous tile's reads complete
    // ---- stage K (swizzled rows) and V (transposed, swizzled keys)
    *(bf16x8*)(&Ks[srow][(sch ^ (srow & 7)) << 3]) = kr;
#pragma unroll
    for (int j = 0; j < 8; ++j) {
      const int keyp = srow ^ ((j ^ sch) << 3);   // xorv(d)=(d&7)^((d>>3)&7)
      Vt[(sch << 3) + j][keyp] = vr[j];
    }
    __syncthreads();   // tiles ready

    // ---- issue next tile's global loads (in flight during compute)
    if (nt < qbB) {
      const int row = ((nt + 1) << 6) + srow;
      kr = *(const bf16x8*)(Kg + (size_t)row * QKV_LD + (sch << 3));
      vr = *(const bf16x8*)(Vg + (size_t)row * QKV_LD + (sch << 3));
    }

    if (nt <= myqb)
      qtile_step(st, myqb, nt, ws, lq, seg, Ks, Vt, Ps[wid]);
  }

  qtile_store(st, out, myqb, h, ws, lq, seg);
}

// ---------------------------------------------------------------------------
extern "C" void kernel_launch(void* const* d_in, const int* in_sizes, int n_in,
                              void* d_out, int out_size, void* d_ws, size_t ws_size,
                              hipStream_t stream) {
  (void)in_sizes; (void)n_in; (void)out_size; (void)ws_size;
  const float* hidden = (const float*)d_in[0];
  const float* w_qkv  = (const float*)d_in[1];
  const float* b_qkv  = (const float*)d_in[2];
  const float* w_out  = (const float*)d_in[3];
  const float* b_out  = (const float*)d_in[4];
  float* out = (float*)d_out;

  bf16* qkvbuf  = (bf16*)d_ws;                            // [2048][6144]
  bf16* attnbuf = qkvbuf  + (size_t)S_LEN * (3 * DM);     // [2048][2048]
  bf16* hidb    = attnbuf + (size_t)S_LEN * DM;           // [2048][2048]
  bf16* wqkvb   = hidb    + (size_t)S_LEN * DM;           // [6144][2048]
  bf16* woutb   = wqkvb   + (size_t)(3 * DM) * DM;        // [2048][2048]

  dim3 blk(256);
  // fused f32 -> bf16 conversions (one launch)
  cvt3_f32_bf16<<<dim3(2048), blk, 0, stream>>>(
      hidden, hidb, (S_LEN * DM) / 8,
      w_qkv, wqkvb, (3 * DM * DM) / 8,
      w_out, woutb, (DM * DM) / 8);
  // QKV projection: M=2048, N=6144, K=2048 (128x128 tiles, dbuf pipeline)
  gemm_bt<128, 128, 2, 2, bf16><<<dim3(48, 16), blk, 0, stream>>>(
      hidb, wqkvb, b_qkv, qkvbuf, S_LEN, 3 * DM, DM);
  // Flash causal attention: paired q-tiles (i, 31-i), 8 waves per block
  attn_flash<<<dim3(16, NH), dim3(512), 0, stream>>>(qkvbuf, attnbuf);
  // Output projection: M=2048, N=2048, K=2048 (64x128 tiles -> 512 blocks)
  gemm_bt<64, 128, 1, 4, float><<<dim3(16, 32), blk, 0, stream>>>(
      attnbuf, woutb, b_out, out, S_LEN, DM, DM);
}

// Round 10
// 155.842 us; speedup vs baseline: 5.7230x; 1.0501x over previous
//
#include <hip/hip_runtime.h>
#include <hip/hip_bf16.h>

typedef __bf16 bf16;
typedef __attribute__((ext_vector_type(8))) __bf16 bf16x8;
typedef __attribute__((ext_vector_type(4))) float f32x4;

#define S_LEN 2048
#define DM 2048
#define NH 32
#define HD 64
#define QKV_LD 6144
// SCALE * log2(e): QK^T scores land directly in log2 domain
#define SCALE2 0.18033688011112042f
#define DEFER_THR 8.0f

// 2^x via v_exp_f32 (gfx9 v_exp IS base-2 exp).
__device__ __forceinline__ float fast_exp2(float x) {
  return __builtin_amdgcn_exp2f(x);
}

// Async global->LDS, 16B per lane. LDS dest must be wave-uniform base; data
// lands at base + lane*16.
__device__ __forceinline__ void gload_lds16(const bf16* g, const bf16* l) {
  __builtin_amdgcn_global_load_lds(
      (const __attribute__((address_space(1))) void*)(uintptr_t)g,
      (__attribute__((address_space(3))) void*)(uint32_t)(uintptr_t)l,
      16, 0, 0);
}

// DPP cross-lane move (VALU pipe — no LDS latency).
template <int CTRL>
__device__ __forceinline__ float fdpp(float x) {
  return __builtin_bit_cast(float,
      __builtin_amdgcn_update_dpp(0, __builtin_bit_cast(int, x), CTRL, 0xF, 0xF, true));
}
// Exact 16-lane butterfly all-reduce: masks {1,2,7,15} are GF(2)-independent.
__device__ __forceinline__ float red16_max(float x) {
  x = fmaxf(x, fdpp<0xB1>(x));    // quad_perm [1,0,3,2]  : xor 1
  x = fmaxf(x, fdpp<0x4E>(x));    // quad_perm [2,3,0,1]  : xor 2
  x = fmaxf(x, fdpp<0x141>(x));   // row_half_mirror      : xor 7
  x = fmaxf(x, fdpp<0x140>(x));   // row_mirror           : xor 15
  return x;
}
__device__ __forceinline__ float red16_sum(float x) {
  x += fdpp<0xB1>(x);
  x += fdpp<0x4E>(x);
  x += fdpp<0x141>(x);
  x += fdpp<0x140>(x);
  return x;
}

// ---------------------------------------------------------------------------
// Fused f32 -> bf16 conversion over three arrays (one launch, grid-stride)
// ---------------------------------------------------------------------------
__global__ __launch_bounds__(256) void cvt3_f32_bf16(
    const float* __restrict__ s0, bf16* __restrict__ d0, const int n0,
    const float* __restrict__ s1, bf16* __restrict__ d1, const int n1,
    const float* __restrict__ s2, bf16* __restrict__ d2, const int n2)
{
  const int total = n0 + n1 + n2;
  const int stride = gridDim.x * blockDim.x;
  for (int i = blockIdx.x * blockDim.x + threadIdx.x; i < total; i += stride) {
    const float* s; bf16* d; int j = i;
    if (j < n0)            { s = s0; d = d0; }
    else if (j - n0 < n1)  { s = s1; d = d1; j -= n0; }
    else                   { s = s2; d = d2; j -= n0 + n1; }
    const f32x4 a = *(const f32x4*)(s + (size_t)j * 8);
    const f32x4 b = *(const f32x4*)(s + (size_t)j * 8 + 4);
    bf16x8 r;
    r[0] = (bf16)a[0]; r[1] = (bf16)a[1]; r[2] = (bf16)a[2]; r[3] = (bf16)a[3];
    r[4] = (bf16)b[0]; r[5] = (bf16)b[1]; r[6] = (bf16)b[2]; r[7] = (bf16)b[3];
    *(bf16x8*)(d + (size_t)j * 8) = r;
  }
}

// ---------------------------------------------------------------------------
// Big-tile pipelined GEMM for QKV: C[M][N] = A @ W^T + bias.
// BM=256 BN=192 BK=64, 512 threads (8 waves, 2Mx4N; wave tile 128x48).
// Grid must be (N/192, M/256) = 256 blocks = 1/CU.
// Double-buffered LDS (112KB), depth-1 counted-vmcnt pipeline (T3/T4):
// never drains vmcnt to 0 in steady state. T2 XOR swizzle (chunk ^= row&7)
// applied on the pre-swizzled global SOURCE + the swizzled ds_read (linear
// gload_lds dest, rule #21).
// ---------------------------------------------------------------------------
template <typename TO>
__global__ __launch_bounds__(512, 2) void gemm_bt_big(
    const bf16* __restrict__ A, const bf16* __restrict__ W,
    const float* __restrict__ bias, TO* __restrict__ C,
    const int M, const int N, const int K)
{
  constexpr int BUFE = (256 + 192) * 64;           // elems per buffer
  __shared__ __align__(16) bf16 lds[2 * BUFE];     // 112 KB
  const int tid  = threadIdx.x;
  const int lane = tid & 63;
  const int wid  = tid >> 6;                       // 0..7
  const int wr = wid >> 2, wc = wid & 3;           // 2 x 4 waves
  const int row0 = blockIdx.y << 8;                // *256
  const int col0 = blockIdx.x * 192;
  const int lq = lane & 15, seg = lane >> 4;

  const f32x4 fz = {0.f, 0.f, 0.f, 0.f};
  f32x4 acc[8][3];
#pragma unroll
  for (int i = 0; i < 8; ++i)
#pragma unroll
    for (int j = 0; j < 3; ++j) acc[i][j] = fz;

  // stage K-tile kt into buffer b: A panel [256][64], B panel [192][64],
  // linear LDS layout, inverse-swizzled global source (chunk16 ^= row&7).
  auto stage = [&](const int kt, const int b) {
    const int k0 = kt << 6;
    bf16* Ab = lds + b * BUFE;
    bf16* Bb = Ab + 256 * 64;
#pragma unroll
    for (int c = 0; c < 4; ++c) {                  // A: 32KB = 4 x 8KB
      const int off16 = (c << 9) + tid;            // 16B-unit linear index
      const int row = off16 >> 3;                  // [256] rows of 128B
      const int ch  = (off16 & 7) ^ (row & 7);     // pre-swizzled source chunk
      gload_lds16(A + (size_t)(row0 + row) * K + k0 + (ch << 3),
                  Ab + (size_t)((c << 9) + (wid << 6)) * 8);
    }
#pragma unroll
    for (int c = 0; c < 3; ++c) {                  // B: 24KB = 3 x 8KB
      const int off16 = (c << 9) + tid;
      const int row = off16 >> 3;                  // [192] rows
      const int ch  = (off16 & 7) ^ (row & 7);
      gload_lds16(W + (size_t)(col0 + row) * K + k0 + (ch << 3),
                  Bb + (size_t)((c << 9) + (wid << 6)) * 8);
    }
  };

  const int nt = K >> 6;                           // 32 K-tiles
  stage(0, 0);

  for (int t = 0; t < nt; ++t) {
    asm volatile("" ::: "memory");
    __builtin_amdgcn_s_barrier();                  // frees buf (t+1)&1 (read at t-1)
    asm volatile("" ::: "memory");
    if (t + 1 < nt) {
      stage(t + 1, (t + 1) & 1);                   // loads fly across this tile
      asm volatile("s_waitcnt vmcnt(7)" ::: "memory");   // tile t landed (mine)
    } else {
      asm volatile("s_waitcnt vmcnt(0)" ::: "memory");   // tail drain
    }
    __builtin_amdgcn_s_barrier();                  // tile t landed (all waves)
    asm volatile("" ::: "memory");

    const bf16* Ab = lds + (t & 1) * BUFE;
    const bf16* Bb = Ab + 256 * 64;
#pragma unroll
    for (int kk = 0; kk < 2; ++kk) {               // K=64 as 2 x K32
      bf16x8 af[8], bfr[3];
#pragma unroll
      for (int i = 0; i < 8; ++i) {
        const int row = (wr << 7) + (i << 4) + lq;
        af[i] = *(const bf16x8*)(Ab + row * 64 +
                 ((((kk << 2) + seg) ^ (row & 7)) << 3));
      }
#pragma unroll
      for (int j = 0; j < 3; ++j) {
        const int row = wc * 48 + (j << 4) + lq;
        bfr[j] = *(const bf16x8*)(Bb + row * 64 +
                 ((((kk << 2) + seg) ^ (row & 7)) << 3));
      }
      __builtin_amdgcn_s_setprio(1);
#pragma unroll
      for (int i = 0; i < 8; ++i)
#pragma unroll
        for (int j = 0; j < 3; ++j)
          acc[i][j] = __builtin_amdgcn_mfma_f32_16x16x32_bf16(af[i], bfr[j], acc[i][j], 0, 0, 0);
      __builtin_amdgcn_s_setprio(0);
    }
  }

  // Epilogue: C/D layout row=(lane>>4)*4+r, col=lane&15
#pragma unroll
  for (int j = 0; j < 3; ++j) {
    const int col = col0 + wc * 48 + (j << 4) + lq;
    const float bv = bias[col];
#pragma unroll
    for (int i = 0; i < 8; ++i) {
      const int rbase = row0 + (wr << 7) + (i << 4) + (seg << 2);
#pragma unroll
      for (int r = 0; r < 4; ++r)
        C[(size_t)(rbase + r) * N + col] = (TO)(acc[i][j][r] + bv);
    }
  }
}

// ---------------------------------------------------------------------------
// GEMM (small tiles, out-proj): T3 minimum 2-phase dbuf, 1 barrier/K-step.
// ---------------------------------------------------------------------------
template <int BM, int BN, int WRN, int WCN, typename TO>
__global__ __launch_bounds__(256) void gemm_bt(
    const bf16* __restrict__ A, const bf16* __restrict__ W,
    const float* __restrict__ bias, TO* __restrict__ C,
    const int M, const int N, const int K)
{
  constexpr int WM = BM / WRN;
  constexpr int WN = BN / WCN;
  constexpr int MI = WM / 16;
  constexpr int NI = WN / 16;
  constexpr int CA = (BM * 32) / 2048;
  constexpr int CB = (BN * 32) / 2048;
  constexpr int BUF = (BM + BN) * 32;
  __shared__ __align__(16) bf16 lds[2 * BUF];
  const int tid  = threadIdx.x;
  const int lane = tid & 63;
  const int wid  = tid >> 6;
  const int wr = wid / WCN, wc = wid % WCN;
  const int row0 = blockIdx.y * BM, col0 = blockIdx.x * BN;
  const int lq = lane & 15, seg = lane >> 4;

  const f32x4 fzero = {0.f, 0.f, 0.f, 0.f};
  f32x4 acc[MI][NI];
#pragma unroll
  for (int i = 0; i < MI; ++i)
#pragma unroll
    for (int j = 0; j < NI; ++j) acc[i][j] = fzero;

  auto stage = [&](const int kt, const int b) {
    const int k0 = kt << 5;
    bf16* Ab = lds + b * BUF;
    bf16* Bb = Ab + BM * 32;
#pragma unroll
    for (int c = 0; c < CA; ++c) {
      const int idx = (c << 8) + tid;
      const int r = idx >> 2, ch = idx & 3;
      gload_lds16(A + (size_t)(row0 + r) * K + (k0 + (ch << 3)),
                  Ab + (size_t)((c << 8) + (wid << 6)) * 8);
    }
#pragma unroll
    for (int c = 0; c < CB; ++c) {
      const int idx = (c << 8) + tid;
      const int r = idx >> 2, ch = idx & 3;
      gload_lds16(W + (size_t)(col0 + r) * K + (k0 + (ch << 3)),
                  Bb + (size_t)((c << 8) + (wid << 6)) * 8);
    }
  };

  const int nk = K >> 5;
  stage(0, 0);
  __syncthreads();

  int cur = 0;
  for (int kt = 0; kt < nk; ++kt) {
    if (kt + 1 < nk) stage(kt + 1, cur ^ 1);
    const bf16* Ab = lds + cur * BUF;
    const bf16* Bb = Ab + BM * 32;
    bf16x8 af[MI], bfr[NI];
#pragma unroll
    for (int i = 0; i < MI; ++i)
      af[i]  = *(const bf16x8*)(Ab + (wr * WM + (i << 4) + lq) * 32 + seg * 8);
#pragma unroll
    for (int j = 0; j < NI; ++j)
      bfr[j] = *(const bf16x8*)(Bb + (wc * WN + (j << 4) + lq) * 32 + seg * 8);
#pragma unroll
    for (int i = 0; i < MI; ++i)
#pragma unroll
      for (int j = 0; j < NI; ++j)
        acc[i][j] = __builtin_amdgcn_mfma_f32_16x16x32_bf16(af[i], bfr[j], acc[i][j], 0, 0, 0);
    __syncthreads();
    cur ^= 1;
  }

#pragma unroll
  for (int j = 0; j < NI; ++j) {
    const int col = col0 + wc * WN + (j << 4) + lq;
    const float bv = bias[col];
#pragma unroll
    for (int i = 0; i < MI; ++i) {
      const int rbase = row0 + wr * WM + (i << 4) + (seg << 2);
#pragma unroll
      for (int r = 0; r < 4; ++r)
        C[(size_t)(rbase + r) * N + col] = (TO)(acc[i][j][r] + bv);
    }
  }
}

// ---------------------------------------------------------------------------
// Per-q-tile flash state (one 16-row slice per wave).
// ---------------------------------------------------------------------------
struct QTile {
  bf16x8 qf[2];    // pre-scaled by SCALE*log2e
  f32x4  o[4];
  float  m[4], l[4];
};

__device__ __forceinline__ void qtile_init(QTile& st, const bf16* Qg,
                                           const int lq, const int seg) {
  const bf16x8 r0 = *(const bf16x8*)(Qg + (size_t)lq * QKV_LD + seg * 8);
  const bf16x8 r1 = *(const bf16x8*)(Qg + (size_t)lq * QKV_LD + 32 + seg * 8);
#pragma unroll
  for (int j = 0; j < 8; ++j) {
    st.qf[0][j] = (bf16)((float)r0[j] * SCALE2);
    st.qf[1][j] = (bf16)((float)r1[j] * SCALE2);
  }
  const f32x4 fz = {0.f, 0.f, 0.f, 0.f};
#pragma unroll
  for (int r = 0; r < 4; ++r) { st.o[r] = fz; st.m[r] = -1e30f; st.l[r] = 0.f; }
}

// QK^T -> mask -> online softmax (log2 domain, defer-max) -> P -> PV.
__device__ __forceinline__ void qtile_step(
    QTile& st, const int qb, const int nt,
    const int ws, const int lq, const int seg,
    const bf16 (&Ks)[64][64], const bf16 (&Vt)[64][64], bf16 (&Psw)[16][64])
{
  const f32x4 fz = {0.f, 0.f, 0.f, 0.f};
  f32x4 s[4];
  __builtin_amdgcn_s_setprio(1);
#pragma unroll
  for (int ct = 0; ct < 4; ++ct) {
    s[ct] = fz;
#pragma unroll
    for (int ks = 0; ks < 2; ++ks) {
      const int blk = ((ks << 2) + seg) ^ (lq & 7);
      const bf16x8 kf = *(const bf16x8*)(&Ks[(ct << 4) + lq][blk << 3]);
      s[ct] = __builtin_amdgcn_mfma_f32_16x16x32_bf16(st.qf[ks], kf, s[ct], 0, 0, 0);
    }
  }
  __builtin_amdgcn_s_setprio(0);

  // causal mask (diagonal tile only); scores already scaled via Q
  if (nt == qb) {
#pragma unroll
    for (int ct = 0; ct < 4; ++ct) {
      const int key = (nt << 6) + (ct << 4) + lq;
#pragma unroll
      for (int r = 0; r < 4; ++r) {
        const int qrow = (qb << 6) + (ws << 4) + (seg << 2) + r;
        if (key > qrow) s[ct][r] = -1e30f;
      }
    }
  }

  // online softmax, log2 domain, defer-max (skip rescale within THR)
#pragma unroll
  for (int r = 0; r < 4; ++r) {
    float tm = fmaxf(fmaxf(s[0][r], s[1][r]), fmaxf(s[2][r], s[3][r]));
    tm = red16_max(tm);
    if (tm > st.m[r] + DEFER_THR) {      // rescale path (rare)
      const float sc = fast_exp2(st.m[r] - tm);
      st.m[r] = tm;
      st.l[r] *= sc;
#pragma unroll
      for (int dt = 0; dt < 4; ++dt) st.o[dt][r] *= sc;
    }
    float rs = 0.f;
#pragma unroll
    for (int ct = 0; ct < 4; ++ct) {
      const float p = fast_exp2(s[ct][r] - st.m[r]);   // bounded by 2^THR
      s[ct][r] = p;
      rs += p;
    }
    rs = red16_sum(rs);
    st.l[r] += rs;
  }

  // P -> per-wave LDS (A-frag layout source), swizzled cols
#pragma unroll
  for (int ct = 0; ct < 4; ++ct)
#pragma unroll
    for (int r = 0; r < 4; ++r) {
      const int q = (seg << 2) + r;
      const int colp = ((ct << 4) + lq) ^ ((q & 7) << 3);
      Psw[q][colp] = (bf16)s[ct][r];
    }

  // PV: O += P[16][64] @ V[64][64]
  __builtin_amdgcn_s_setprio(1);
#pragma unroll
  for (int ks = 0; ks < 2; ++ks) {
    const int blkp = ((ks << 2) + seg) ^ (lq & 7);
    const bf16x8 af = *(const bf16x8*)(&Psw[lq][blkp << 3]);
#pragma unroll
    for (int dt = 0; dt < 4; ++dt) {
      const int xv = (lq & 7) ^ (((dt << 1) + (lq >> 3)) & 7);
      const int blkv = ((ks << 2) + seg) ^ xv;
      const bf16x8 bv = *(const bf16x8*)(&Vt[(dt << 4) + lq][blkv << 3]);
      st.o[dt] = __builtin_amdgcn_mfma_f32_16x16x32_bf16(af, bv, st.o[dt], 0, 0, 0);
    }
  }
  __builtin_amdgcn_s_setprio(0);
}

__device__ __forceinline__ void qtile_store(
    const QTile& st, bf16* __restrict__ out, const int qb, const int h,
    const int ws, const int lq, const int seg)
{
  float rinv[4];
#pragma unroll
  for (int r = 0; r < 4; ++r) rinv[r] = 1.f / st.l[r];
#pragma unroll
  for (int dt = 0; dt < 4; ++dt)
#pragma unroll
    for (int r = 0; r < 4; ++r) {
      const int qrow = (qb << 6) + (ws << 4) + (seg << 2) + r;
      out[(size_t)qrow * DM + h * HD + (dt << 4) + lq] =
          (bf16)(st.o[dt][r] * rinv[r]);
    }
}

// ---------------------------------------------------------------------------
// Flash-style causal attention, 8-wave blocks with wrap-paired q-tiles.
// ---------------------------------------------------------------------------
__global__ __launch_bounds__(512) void attn_flash(
    const bf16* __restrict__ qkv, bf16* __restrict__ out)
{
  __shared__ __align__(16) bf16 Ks[64][64];       // [key][d], col-swizzled
  __shared__ __align__(16) bf16 Vt[64][64];       // [d][key], key-swizzled
  __shared__ __align__(16) bf16 Ps[8][16][64];    // per-wave P, col-swizzled
  const int qbA = blockIdx.x;                     // 0..15 (short range)
  const int qbB = 31 - qbA;                       // 31..16 (long range)
  const int h   = blockIdx.y;
  const int tid = threadIdx.x;
  const int lane = tid & 63, wid = tid >> 6;      // wid 0..7
  const int lq = lane & 15, seg = lane >> 4;
  const int myqb = (wid < 4) ? qbA : qbB;
  const int ws   = wid & 3;                       // 16-row slice within tile

  const bf16* Kg = qkv + DM + h * HD;
  const bf16* Vg = qkv + 2 * DM + h * HD;

  QTile st;
  qtile_init(st, qkv + (size_t)(myqb * 64 + ws * 16) * QKV_LD + h * HD, lq, seg);

  const int srow = tid >> 3, sch = tid & 7;  // staging: row 0..63, chunk 0..7

  // prefetch KV tile 0 into registers
  bf16x8 kr = *(const bf16x8*)(Kg + (size_t)srow * QKV_LD + (sch << 3));
  bf16x8 vr = *(const bf16x8*)(Vg + (size_t)srow * QKV_LD + (sch << 3));

  for (int nt = 0; nt <= qbB; ++nt) {
    __syncthreads();   // previous tile's reads complete
    // ---- stage K (swizzled rows) and V (transposed, swizzled keys)
    *(bf16x8*)(&Ks[srow][(sch ^ (srow & 7)) << 3]) = kr;
#pragma unroll
    for (int j = 0; j < 8; ++j) {
      const int keyp = srow ^ ((j ^ sch) << 3);   // xorv(d)=(d&7)^((d>>3)&7)
      Vt[(sch << 3) + j][keyp] = vr[j];
    }
    __syncthreads();   // tiles ready

    // ---- issue next tile's global loads (in flight during compute)
    if (nt < qbB) {
      const int row = ((nt + 1) << 6) + srow;
      kr = *(const bf16x8*)(Kg + (size_t)row * QKV_LD + (sch << 3));
      vr = *(const bf16x8*)(Vg + (size_t)row * QKV_LD + (sch << 3));
    }

    if (nt <= myqb)
      qtile_step(st, myqb, nt, ws, lq, seg, Ks, Vt, Ps[wid]);
  }

  qtile_store(st, out, myqb, h, ws, lq, seg);
}

// ---------------------------------------------------------------------------
extern "C" void kernel_launch(void* const* d_in, const int* in_sizes, int n_in,
                              void* d_out, int out_size, void* d_ws, size_t ws_size,
                              hipStream_t stream) {
  (void)in_sizes; (void)n_in; (void)out_size; (void)ws_size;
  const float* hidden = (const float*)d_in[0];
  const float* w_qkv  = (const float*)d_in[1];
  const float* b_qkv  = (const float*)d_in[2];
  const float* w_out  = (const float*)d_in[3];
  const float* b_out  = (const float*)d_in[4];
  float* out = (float*)d_out;

  bf16* qkvbuf  = (bf16*)d_ws;                            // [2048][6144]
  bf16* attnbuf = qkvbuf  + (size_t)S_LEN * (3 * DM);     // [2048][2048]
  bf16* hidb    = attnbuf + (size_t)S_LEN * DM;           // [2048][2048]
  bf16* wqkvb   = hidb    + (size_t)S_LEN * DM;           // [6144][2048]
  bf16* woutb   = wqkvb   + (size_t)(3 * DM) * DM;        // [2048][2048]

  dim3 blk(256);
  // fused f32 -> bf16 conversions (one launch)
  cvt3_f32_bf16<<<dim3(2048), blk, 0, stream>>>(
      hidden, hidb, (S_LEN * DM) / 8,
      w_qkv, wqkvb, (3 * DM * DM) / 8,
      w_out, woutb, (DM * DM) / 8);
  // QKV projection: M=2048, N=6144, K=2048 — 256x192 tiles, 256 blocks (1/CU)
  gemm_bt_big<bf16><<<dim3(32, 8), dim3(512), 0, stream>>>(
      hidb, wqkvb, b_qkv, qkvbuf, S_LEN, 3 * DM, DM);
  // Flash causal attention: paired q-tiles (i, 31-i), 8 waves per block
  attn_flash<<<dim3(16, NH), dim3(512), 0, stream>>>(qkvbuf, attnbuf);
  // Output projection: M=2048, N=2048, K=2048 (64x128 tiles -> 512 blocks)
  gemm_bt<64, 128, 1, 4, float><<<dim3(16, 32), blk, 0, stream>>>(
      attnbuf, woutb, b_out, out, S_LEN, DM, DM);
}

// Round 11
// 148.902 us; speedup vs baseline: 5.9898x; 1.0466x over previous
//
#include <hip/hip_runtime.h>
#include <hip/hip_bf16.h>

typedef __bf16 bf16;
typedef __attribute__((ext_vector_type(8))) __bf16 bf16x8;
typedef __attribute__((ext_vector_type(4))) float f32x4;

#define S_LEN 2048
#define DM 2048
#define NH 32
#define HD 64
#define QKV_LD 6144
// SCALE * log2(e): QK^T scores land directly in log2 domain
#define SCALE2 0.18033688011112042f
#define DEFER_THR 8.0f

// 2^x via v_exp_f32 (gfx9 v_exp IS base-2 exp).
__device__ __forceinline__ float fast_exp2(float x) {
  return __builtin_amdgcn_exp2f(x);
}

// Async global->LDS, 16B per lane. LDS dest must be wave-uniform base; data
// lands at base + lane*16.
__device__ __forceinline__ void gload_lds16(const bf16* g, const bf16* l) {
  __builtin_amdgcn_global_load_lds(
      (const __attribute__((address_space(1))) void*)(uintptr_t)g,
      (__attribute__((address_space(3))) void*)(uint32_t)(uintptr_t)l,
      16, 0, 0);
}

// Compile-time counted vmcnt (inline asm needs a literal).
template <int N>
__device__ __forceinline__ void waitcnt_vm() {
  if constexpr (N == 0)      asm volatile("s_waitcnt vmcnt(0)" ::: "memory");
  else if constexpr (N == 4) asm volatile("s_waitcnt vmcnt(4)" ::: "memory");
  else if constexpr (N == 5) asm volatile("s_waitcnt vmcnt(5)" ::: "memory");
  else if constexpr (N == 6) asm volatile("s_waitcnt vmcnt(6)" ::: "memory");
  else if constexpr (N == 7) asm volatile("s_waitcnt vmcnt(7)" ::: "memory");
  else if constexpr (N == 8) asm volatile("s_waitcnt vmcnt(8)" ::: "memory");
  else static_assert(N == 0, "add vmcnt case");
}

// DPP cross-lane move (VALU pipe — no LDS latency).
template <int CTRL>
__device__ __forceinline__ float fdpp(float x) {
  return __builtin_bit_cast(float,
      __builtin_amdgcn_update_dpp(0, __builtin_bit_cast(int, x), CTRL, 0xF, 0xF, true));
}
// Exact 16-lane butterfly all-reduce: masks {1,2,7,15} are GF(2)-independent.
__device__ __forceinline__ float red16_max(float x) {
  x = fmaxf(x, fdpp<0xB1>(x));    // quad_perm [1,0,3,2]  : xor 1
  x = fmaxf(x, fdpp<0x4E>(x));    // quad_perm [2,3,0,1]  : xor 2
  x = fmaxf(x, fdpp<0x141>(x));   // row_half_mirror      : xor 7
  x = fmaxf(x, fdpp<0x140>(x));   // row_mirror           : xor 15
  return x;
}
__device__ __forceinline__ float red16_sum(float x) {
  x += fdpp<0xB1>(x);
  x += fdpp<0x4E>(x);
  x += fdpp<0x141>(x);
  x += fdpp<0x140>(x);
  return x;
}

// ---------------------------------------------------------------------------
// Fused f32 -> bf16 conversion over three arrays (one launch, grid-stride)
// ---------------------------------------------------------------------------
__global__ __launch_bounds__(256) void cvt3_f32_bf16(
    const float* __restrict__ s0, bf16* __restrict__ d0, const int n0,
    const float* __restrict__ s1, bf16* __restrict__ d1, const int n1,
    const float* __restrict__ s2, bf16* __restrict__ d2, const int n2)
{
  const int total = n0 + n1 + n2;
  const int stride = gridDim.x * blockDim.x;
  for (int i = blockIdx.x * blockDim.x + threadIdx.x; i < total; i += stride) {
    const float* s; bf16* d; int j = i;
    if (j < n0)            { s = s0; d = d0; }
    else if (j - n0 < n1)  { s = s1; d = d1; j -= n0; }
    else                   { s = s2; d = d2; j -= n0 + n1; }
    const f32x4 a = *(const f32x4*)(s + (size_t)j * 8);
    const f32x4 b = *(const f32x4*)(s + (size_t)j * 8 + 4);
    bf16x8 r;
    r[0] = (bf16)a[0]; r[1] = (bf16)a[1]; r[2] = (bf16)a[2]; r[3] = (bf16)a[3];
    r[4] = (bf16)b[0]; r[5] = (bf16)b[1]; r[6] = (bf16)b[2]; r[7] = (bf16)b[3];
    *(bf16x8*)(d + (size_t)j * 8) = r;
  }
}

// ---------------------------------------------------------------------------
// Pipelined GEMM: C[M][N] = A @ W^T + bias.  BK=64, NT threads (NW waves,
// WRN x WCN), double-buffered LDS, depth-1 counted-vmcnt pipeline (never
// drains vmcnt to 0 in steady state; raw s_barrier, no syncthreads drain).
// T2 swizzle: linear gload_lds dest + inverse-swizzled global SOURCE
// (chunk ^= row&7) + same XOR on ds_read (rule #21).
// Grid must be (N/BN, M/BM). Tile sized for 2 blocks/CU (TLP overlap, m114).
// ---------------------------------------------------------------------------
template <int BM, int BN, int WRN, int WCN, int NT, int MINW, typename TO>
__global__ __launch_bounds__(NT, MINW) void gemm_pipe(
    const bf16* __restrict__ A, const bf16* __restrict__ W,
    const float* __restrict__ bias, TO* __restrict__ C,
    const int M, const int N, const int K)
{
  constexpr int WM = BM / WRN, WN = BN / WCN;
  constexpr int MI = WM / 16, NI = WN / 16;
  constexpr int CA = (BM * 64 * 2) / (NT * 16);   // staging chunks (A)
  constexpr int CB = (BN * 64 * 2) / (NT * 16);   // staging chunks (B)
  constexpr int BUFE = (BM + BN) * 64;            // elems per buffer
  __shared__ __align__(16) bf16 lds[2 * BUFE];
  const int tid  = threadIdx.x;
  const int lane = tid & 63;
  const int wid  = tid >> 6;
  const int wr = wid / WCN, wc = wid % WCN;
  const int row0 = blockIdx.y * BM, col0 = blockIdx.x * BN;
  const int lq = lane & 15, seg = lane >> 4;

  const f32x4 fz = {0.f, 0.f, 0.f, 0.f};
  f32x4 acc[MI][NI];
#pragma unroll
  for (int i = 0; i < MI; ++i)
#pragma unroll
    for (int j = 0; j < NI; ++j) acc[i][j] = fz;

  auto stage = [&](const int kt, const int b) {
    const int k0 = kt << 6;
    bf16* Ab = lds + b * BUFE;
    bf16* Bb = Ab + BM * 64;
#pragma unroll
    for (int c = 0; c < CA; ++c) {
      const int off16 = c * NT + tid;              // 16B-unit linear index
      const int row = off16 >> 3;                  // 128B rows (BK=64 bf16)
      const int ch  = (off16 & 7) ^ (row & 7);     // pre-swizzled source
      gload_lds16(A + (size_t)(row0 + row) * K + k0 + (ch << 3),
                  Ab + (size_t)(c * NT + (wid << 6)) * 8);
    }
#pragma unroll
    for (int c = 0; c < CB; ++c) {
      const int off16 = c * NT + tid;
      const int row = off16 >> 3;
      const int ch  = (off16 & 7) ^ (row & 7);
      gload_lds16(W + (size_t)(col0 + row) * K + k0 + (ch << 3),
                  Bb + (size_t)(c * NT + (wid << 6)) * 8);
    }
  };

  const int nt = K >> 6;
  stage(0, 0);

  for (int t = 0; t < nt; ++t) {
    asm volatile("" ::: "memory");
    __builtin_amdgcn_s_barrier();                  // frees buf (t+1)&1
    asm volatile("" ::: "memory");
    if (t + 1 < nt) {
      stage(t + 1, (t + 1) & 1);                   // loads fly across tile t
      waitcnt_vm<CA + CB>();                       // tile-t loads landed (mine)
    } else {
      waitcnt_vm<0>();                             // tail drain
    }
    __builtin_amdgcn_s_barrier();                  // tile t landed (all waves)
    asm volatile("" ::: "memory");

    const bf16* Ab = lds + (t & 1) * BUFE;
    const bf16* Bb = Ab + BM * 64;
#pragma unroll
    for (int kk = 0; kk < 2; ++kk) {               // K=64 as 2 x K32
      bf16x8 af[MI], bfr[NI];
#pragma unroll
      for (int i = 0; i < MI; ++i) {
        const int row = wr * WM + (i << 4) + lq;
        af[i] = *(const bf16x8*)(Ab + row * 64 +
                 ((((kk << 2) + seg) ^ (row & 7)) << 3));
      }
#pragma unroll
      for (int j = 0; j < NI; ++j) {
        const int row = wc * WN + (j << 4) + lq;
        bfr[j] = *(const bf16x8*)(Bb + row * 64 +
                 ((((kk << 2) + seg) ^ (row & 7)) << 3));
      }
      __builtin_amdgcn_s_setprio(1);
#pragma unroll
      for (int i = 0; i < MI; ++i)
#pragma unroll
        for (int j = 0; j < NI; ++j)
          acc[i][j] = __builtin_amdgcn_mfma_f32_16x16x32_bf16(af[i], bfr[j], acc[i][j], 0, 0, 0);
      __builtin_amdgcn_s_setprio(0);
    }
  }

  // Epilogue: C/D layout row=(lane>>4)*4+r, col=lane&15
#pragma unroll
  for (int j = 0; j < NI; ++j) {
    const int col = col0 + wc * WN + (j << 4) + lq;
    const float bv = bias[col];
#pragma unroll
    for (int i = 0; i < MI; ++i) {
      const int rbase = row0 + wr * WM + (i << 4) + (seg << 2);
#pragma unroll
      for (int r = 0; r < 4; ++r)
        C[(size_t)(rbase + r) * N + col] = (TO)(acc[i][j][r] + bv);
    }
  }
}

// ---------------------------------------------------------------------------
// Per-q-tile flash state (one 16-row slice per wave).
// ---------------------------------------------------------------------------
struct QTile {
  bf16x8 qf[2];    // pre-scaled by SCALE*log2e
  f32x4  o[4];
  float  m[4], l[4];
};

__device__ __forceinline__ void qtile_init(QTile& st, const bf16* Qg,
                                           const int lq, const int seg) {
  const bf16x8 r0 = *(const bf16x8*)(Qg + (size_t)lq * QKV_LD + seg * 8);
  const bf16x8 r1 = *(const bf16x8*)(Qg + (size_t)lq * QKV_LD + 32 + seg * 8);
#pragma unroll
  for (int j = 0; j < 8; ++j) {
    st.qf[0][j] = (bf16)((float)r0[j] * SCALE2);
    st.qf[1][j] = (bf16)((float)r1[j] * SCALE2);
  }
  const f32x4 fz = {0.f, 0.f, 0.f, 0.f};
#pragma unroll
  for (int r = 0; r < 4; ++r) { st.o[r] = fz; st.m[r] = -1e30f; st.l[r] = 0.f; }
}

// QK^T -> mask -> online softmax (log2 domain, defer-max) -> P -> PV.
__device__ __forceinline__ void qtile_step(
    QTile& st, const int qb, const int nt,
    const int ws, const int lq, const int seg,
    const bf16 (&Ks)[64][64], const bf16 (&Vt)[64][64], bf16 (&Psw)[16][64])
{
  const f32x4 fz = {0.f, 0.f, 0.f, 0.f};
  f32x4 s[4];
  __builtin_amdgcn_s_setprio(1);
#pragma unroll
  for (int ct = 0; ct < 4; ++ct) {
    s[ct] = fz;
#pragma unroll
    for (int ks = 0; ks < 2; ++ks) {
      const int blk = ((ks << 2) + seg) ^ (lq & 7);
      const bf16x8 kf = *(const bf16x8*)(&Ks[(ct << 4) + lq][blk << 3]);
      s[ct] = __builtin_amdgcn_mfma_f32_16x16x32_bf16(st.qf[ks], kf, s[ct], 0, 0, 0);
    }
  }
  __builtin_amdgcn_s_setprio(0);

  // causal mask (diagonal tile only); scores already scaled via Q
  if (nt == qb) {
#pragma unroll
    for (int ct = 0; ct < 4; ++ct) {
      const int key = (nt << 6) + (ct << 4) + lq;
#pragma unroll
      for (int r = 0; r < 4; ++r) {
        const int qrow = (qb << 6) + (ws << 4) + (seg << 2) + r;
        if (key > qrow) s[ct][r] = -1e30f;
      }
    }
  }

  // online softmax, log2 domain, defer-max (skip rescale within THR)
#pragma unroll
  for (int r = 0; r < 4; ++r) {
    float tm = fmaxf(fmaxf(s[0][r], s[1][r]), fmaxf(s[2][r], s[3][r]));
    tm = red16_max(tm);
    if (tm > st.m[r] + DEFER_THR) {      // rescale path (rare)
      const float sc = fast_exp2(st.m[r] - tm);
      st.m[r] = tm;
      st.l[r] *= sc;
#pragma unroll
      for (int dt = 0; dt < 4; ++dt) st.o[dt][r] *= sc;
    }
    float rs = 0.f;
#pragma unroll
    for (int ct = 0; ct < 4; ++ct) {
      const float p = fast_exp2(s[ct][r] - st.m[r]);   // bounded by 2^THR
      s[ct][r] = p;
      rs += p;
    }
    rs = red16_sum(rs);
    st.l[r] += rs;
  }

  // P -> per-wave LDS (A-frag layout source), swizzled cols
#pragma unroll
  for (int ct = 0; ct < 4; ++ct)
#pragma unroll
    for (int r = 0; r < 4; ++r) {
      const int q = (seg << 2) + r;
      const int colp = ((ct << 4) + lq) ^ ((q & 7) << 3);
      Psw[q][colp] = (bf16)s[ct][r];
    }

  // PV: O += P[16][64] @ V[64][64]
  __builtin_amdgcn_s_setprio(1);
#pragma unroll
  for (int ks = 0; ks < 2; ++ks) {
    const int blkp = ((ks << 2) + seg) ^ (lq & 7);
    const bf16x8 af = *(const bf16x8*)(&Psw[lq][blkp << 3]);
#pragma unroll
    for (int dt = 0; dt < 4; ++dt) {
      const int xv = (lq & 7) ^ (((dt << 1) + (lq >> 3)) & 7);
      const int blkv = ((ks << 2) + seg) ^ xv;
      const bf16x8 bv = *(const bf16x8*)(&Vt[(dt << 4) + lq][blkv << 3]);
      st.o[dt] = __builtin_amdgcn_mfma_f32_16x16x32_bf16(af, bv, st.o[dt], 0, 0, 0);
    }
  }
  __builtin_amdgcn_s_setprio(0);
}

__device__ __forceinline__ void qtile_store(
    const QTile& st, bf16* __restrict__ out, const int qb, const int h,
    const int ws, const int lq, const int seg)
{
  float rinv[4];
#pragma unroll
  for (int r = 0; r < 4; ++r) rinv[r] = 1.f / st.l[r];
#pragma unroll
  for (int dt = 0; dt < 4; ++dt)
#pragma unroll
    for (int r = 0; r < 4; ++r) {
      const int qrow = (qb << 6) + (ws << 4) + (seg << 2) + r;
      out[(size_t)qrow * DM + h * HD + (dt << 4) + lq] =
          (bf16)(st.o[dt][r] * rinv[r]);
    }
}

// ---------------------------------------------------------------------------
// Flash-style causal attention, 8-wave blocks with wrap-paired q-tiles.
// ---------------------------------------------------------------------------
__global__ __launch_bounds__(512) void attn_flash(
    const bf16* __restrict__ qkv, bf16* __restrict__ out)
{
  __shared__ __align__(16) bf16 Ks[64][64];       // [key][d], col-swizzled
  __shared__ __align__(16) bf16 Vt[64][64];       // [d][key], key-swizzled
  __shared__ __align__(16) bf16 Ps[8][16][64];    // per-wave P, col-swizzled
  const int qbA = blockIdx.x;                     // 0..15 (short range)
  const int qbB = 31 - qbA;                       // 31..16 (long range)
  const int h   = blockIdx.y;
  const int tid = threadIdx.x;
  const int lane = tid & 63, wid = tid >> 6;      // wid 0..7
  const int lq = lane & 15, seg = lane >> 4;
  const int myqb = (wid < 4) ? qbA : qbB;
  const int ws   = wid & 3;                       // 16-row slice within tile

  const bf16* Kg = qkv + DM + h * HD;
  const bf16* Vg = qkv + 2 * DM + h * HD;

  QTile st;
  qtile_init(st, qkv + (size_t)(myqb * 64 + ws * 16) * QKV_LD + h * HD, lq, seg);

  const int srow = tid >> 3, sch = tid & 7;  // staging: row 0..63, chunk 0..7

  // prefetch KV tile 0 into registers
  bf16x8 kr = *(const bf16x8*)(Kg + (size_t)srow * QKV_LD + (sch << 3));
  bf16x8 vr = *(const bf16x8*)(Vg + (size_t)srow * QKV_LD + (sch << 3));

  for (int nt = 0; nt <= qbB; ++nt) {
    __syncthreads();   // previous tile's reads complete
    // ---- stage K (swizzled rows) and V (transposed, swizzled keys)
    *(bf16x8*)(&Ks[srow][(sch ^ (srow & 7)) << 3]) = kr;
#pragma unroll
    for (int j = 0; j < 8; ++j) {
      const int keyp = srow ^ ((j ^ sch) << 3);   // xorv(d)=(d&7)^((d>>3)&7)
      Vt[(sch << 3) + j][keyp] = vr[j];
    }
    __syncthreads();   // tiles ready

    // ---- issue next tile's global loads (in flight during compute)
    if (nt < qbB) {
      const int row = ((nt + 1) << 6) + srow;
      kr = *(const bf16x8*)(Kg + (size_t)row * QKV_LD + (sch << 3));
      vr = *(const bf16x8*)(Vg + (size_t)row * QKV_LD + (sch << 3));
    }

    if (nt <= myqb)
      qtile_step(st, myqb, nt, ws, lq, seg, Ks, Vt, Ps[wid]);
  }

  qtile_store(st, out, myqb, h, ws, lq, seg);
}

// ---------------------------------------------------------------------------
extern "C" void kernel_launch(void* const* d_in, const int* in_sizes, int n_in,
                              void* d_out, int out_size, void* d_ws, size_t ws_size,
                              hipStream_t stream) {
  (void)in_sizes; (void)n_in; (void)out_size; (void)ws_size;
  const float* hidden = (const float*)d_in[0];
  const float* w_qkv  = (const float*)d_in[1];
  const float* b_qkv  = (const float*)d_in[2];
  const float* w_out  = (const float*)d_in[3];
  const float* b_out  = (const float*)d_in[4];
  float* out = (float*)d_out;

  bf16* qkvbuf  = (bf16*)d_ws;                            // [2048][6144]
  bf16* attnbuf = qkvbuf  + (size_t)S_LEN * (3 * DM);     // [2048][2048]
  bf16* hidb    = attnbuf + (size_t)S_LEN * DM;           // [2048][2048]
  bf16* wqkvb   = hidb    + (size_t)S_LEN * DM;           // [6144][2048]
  bf16* woutb   = wqkvb   + (size_t)(3 * DM) * DM;        // [2048][2048]

  dim3 blk(256);
  // fused f32 -> bf16 conversions (one launch)
  cvt3_f32_bf16<<<dim3(2048), blk, 0, stream>>>(
      hidden, hidb, (S_LEN * DM) / 8,
      w_qkv, wqkvb, (3 * DM * DM) / 8,
      w_out, woutb, (DM * DM) / 8);
  // QKV projection: 128x192 tiles, 512 blocks = 2/CU, counted-vmcnt pipeline
  gemm_pipe<128, 192, 2, 4, 512, 4, bf16><<<dim3(32, 16), dim3(512), 0, stream>>>(
      hidb, wqkvb, b_qkv, qkvbuf, S_LEN, 3 * DM, DM);
  // Flash causal attention: paired q-tiles (i, 31-i), 8 waves per block
  attn_flash<<<dim3(16, NH), dim3(512), 0, stream>>>(qkvbuf, attnbuf);
  // Output projection: 64x128 tiles, 512 blocks = 2/CU, counted-vmcnt pipeline
  gemm_pipe<64, 128, 1, 4, 256, 2, float><<<dim3(16, 32), dim3(256), 0, stream>>>(
      attnbuf, woutb, b_out, out, S_LEN, DM, DM);
}

// Round 12
// 147.753 us; speedup vs baseline: 6.0364x; 1.0078x over previous
//
#include <hip/hip_runtime.h>
#include <hip/hip_bf16.h>

typedef __bf16 bf16;
typedef __attribute__((ext_vector_type(8))) __bf16 bf16x8;
typedef __attribute__((ext_vector_type(4))) float f32x4;

#define S_LEN 2048
#define DM 2048
#define NH 32
#define HD 64
#define QKV_LD 6144
// SCALE * log2(e): QK^T scores land directly in log2 domain
#define SCALE2 0.18033688011112042f
#define DEFER_THR 8.0f

// 2^x via v_exp_f32 (gfx9 v_exp IS base-2 exp).
__device__ __forceinline__ float fast_exp2(float x) {
  return __builtin_amdgcn_exp2f(x);
}

// Async global->LDS, 16B per lane. LDS dest must be wave-uniform base; data
// lands at base + lane*16.
__device__ __forceinline__ void gload_lds16(const bf16* g, const bf16* l) {
  __builtin_amdgcn_global_load_lds(
      (const __attribute__((address_space(1))) void*)(uintptr_t)g,
      (__attribute__((address_space(3))) void*)(uint32_t)(uintptr_t)l,
      16, 0, 0);
}

// Compile-time counted vmcnt (inline asm needs a literal).
template <int N>
__device__ __forceinline__ void waitcnt_vm() {
  if constexpr (N == 0)      asm volatile("s_waitcnt vmcnt(0)" ::: "memory");
  else if constexpr (N == 4) asm volatile("s_waitcnt vmcnt(4)" ::: "memory");
  else if constexpr (N == 5) asm volatile("s_waitcnt vmcnt(5)" ::: "memory");
  else if constexpr (N == 6) asm volatile("s_waitcnt vmcnt(6)" ::: "memory");
  else if constexpr (N == 7) asm volatile("s_waitcnt vmcnt(7)" ::: "memory");
  else if constexpr (N == 8) asm volatile("s_waitcnt vmcnt(8)" ::: "memory");
  else static_assert(N == 0, "add vmcnt case");
}

// DPP cross-lane move (VALU pipe — no LDS latency).
template <int CTRL>
__device__ __forceinline__ float fdpp(float x) {
  return __builtin_bit_cast(float,
      __builtin_amdgcn_update_dpp(0, __builtin_bit_cast(int, x), CTRL, 0xF, 0xF, true));
}
// Exact 16-lane butterfly all-reduce: masks {1,2,7,15} are GF(2)-independent.
__device__ __forceinline__ float red16_max(float x) {
  x = fmaxf(x, fdpp<0xB1>(x));    // quad_perm [1,0,3,2]  : xor 1
  x = fmaxf(x, fdpp<0x4E>(x));    // quad_perm [2,3,0,1]  : xor 2
  x = fmaxf(x, fdpp<0x141>(x));   // row_half_mirror      : xor 7
  x = fmaxf(x, fdpp<0x140>(x));   // row_mirror           : xor 15
  return x;
}
__device__ __forceinline__ float red16_sum(float x) {
  x += fdpp<0xB1>(x);
  x += fdpp<0x4E>(x);
  x += fdpp<0x141>(x);
  x += fdpp<0x140>(x);
  return x;
}

// ---------------------------------------------------------------------------
// Fused f32 -> bf16 conversion over three arrays (one launch, grid-stride)
// ---------------------------------------------------------------------------
__global__ __launch_bounds__(256) void cvt3_f32_bf16(
    const float* __restrict__ s0, bf16* __restrict__ d0, const int n0,
    const float* __restrict__ s1, bf16* __restrict__ d1, const int n1,
    const float* __restrict__ s2, bf16* __restrict__ d2, const int n2)
{
  const int total = n0 + n1 + n2;
  const int stride = gridDim.x * blockDim.x;
  for (int i = blockIdx.x * blockDim.x + threadIdx.x; i < total; i += stride) {
    const float* s; bf16* d; int j = i;
    if (j < n0)            { s = s0; d = d0; }
    else if (j - n0 < n1)  { s = s1; d = d1; j -= n0; }
    else                   { s = s2; d = d2; j -= n0 + n1; }
    const f32x4 a = *(const f32x4*)(s + (size_t)j * 8);
    const f32x4 b = *(const f32x4*)(s + (size_t)j * 8 + 4);
    bf16x8 r;
    r[0] = (bf16)a[0]; r[1] = (bf16)a[1]; r[2] = (bf16)a[2]; r[3] = (bf16)a[3];
    r[4] = (bf16)b[0]; r[5] = (bf16)b[1]; r[6] = (bf16)b[2]; r[7] = (bf16)b[3];
    *(bf16x8*)(d + (size_t)j * 8) = r;
  }
}

// ---------------------------------------------------------------------------
// Pipelined GEMM: C[M][N] = A @ W^T + bias.  BK=64, double-buffered LDS,
// depth-1 counted-vmcnt pipeline, T2 swizzle (rule #21), 2 blocks/CU.
// ---------------------------------------------------------------------------
template <int BM, int BN, int WRN, int WCN, int NT, int MINW, typename TO>
__global__ __launch_bounds__(NT, MINW) void gemm_pipe(
    const bf16* __restrict__ A, const bf16* __restrict__ W,
    const float* __restrict__ bias, TO* __restrict__ C,
    const int M, const int N, const int K)
{
  constexpr int WM = BM / WRN, WN = BN / WCN;
  constexpr int MI = WM / 16, NI = WN / 16;
  constexpr int CA = (BM * 64 * 2) / (NT * 16);   // staging chunks (A)
  constexpr int CB = (BN * 64 * 2) / (NT * 16);   // staging chunks (B)
  constexpr int BUFE = (BM + BN) * 64;            // elems per buffer
  __shared__ __align__(16) bf16 lds[2 * BUFE];
  const int tid  = threadIdx.x;
  const int lane = tid & 63;
  const int wid  = tid >> 6;
  const int wr = wid / WCN, wc = wid % WCN;
  const int row0 = blockIdx.y * BM, col0 = blockIdx.x * BN;
  const int lq = lane & 15, seg = lane >> 4;

  const f32x4 fz = {0.f, 0.f, 0.f, 0.f};
  f32x4 acc[MI][NI];
#pragma unroll
  for (int i = 0; i < MI; ++i)
#pragma unroll
    for (int j = 0; j < NI; ++j) acc[i][j] = fz;

  auto stage = [&](const int kt, const int b) {
    const int k0 = kt << 6;
    bf16* Ab = lds + b * BUFE;
    bf16* Bb = Ab + BM * 64;
#pragma unroll
    for (int c = 0; c < CA; ++c) {
      const int off16 = c * NT + tid;              // 16B-unit linear index
      const int row = off16 >> 3;                  // 128B rows (BK=64 bf16)
      const int ch  = (off16 & 7) ^ (row & 7);     // pre-swizzled source
      gload_lds16(A + (size_t)(row0 + row) * K + k0 + (ch << 3),
                  Ab + (size_t)(c * NT + (wid << 6)) * 8);
    }
#pragma unroll
    for (int c = 0; c < CB; ++c) {
      const int off16 = c * NT + tid;
      const int row = off16 >> 3;
      const int ch  = (off16 & 7) ^ (row & 7);
      gload_lds16(W + (size_t)(col0 + row) * K + k0 + (ch << 3),
                  Bb + (size_t)(c * NT + (wid << 6)) * 8);
    }
  };

  const int nt = K >> 6;
  stage(0, 0);

  for (int t = 0; t < nt; ++t) {
    asm volatile("" ::: "memory");
    __builtin_amdgcn_s_barrier();                  // frees buf (t+1)&1
    asm volatile("" ::: "memory");
    if (t + 1 < nt) {
      stage(t + 1, (t + 1) & 1);                   // loads fly across tile t
      waitcnt_vm<CA + CB>();                       // tile-t loads landed (mine)
    } else {
      waitcnt_vm<0>();                             // tail drain
    }
    __builtin_amdgcn_s_barrier();                  // tile t landed (all waves)
    asm volatile("" ::: "memory");

    const bf16* Ab = lds + (t & 1) * BUFE;
    const bf16* Bb = Ab + BM * 64;
#pragma unroll
    for (int kk = 0; kk < 2; ++kk) {               // K=64 as 2 x K32
      bf16x8 af[MI], bfr[NI];
#pragma unroll
      for (int i = 0; i < MI; ++i) {
        const int row = wr * WM + (i << 4) + lq;
        af[i] = *(const bf16x8*)(Ab + row * 64 +
                 ((((kk << 2) + seg) ^ (row & 7)) << 3));
      }
#pragma unroll
      for (int j = 0; j < NI; ++j) {
        const int row = wc * WN + (j << 4) + lq;
        bfr[j] = *(const bf16x8*)(Bb + row * 64 +
                 ((((kk << 2) + seg) ^ (row & 7)) << 3));
      }
      __builtin_amdgcn_s_setprio(1);
#pragma unroll
      for (int i = 0; i < MI; ++i)
#pragma unroll
        for (int j = 0; j < NI; ++j)
          acc[i][j] = __builtin_amdgcn_mfma_f32_16x16x32_bf16(af[i], bfr[j], acc[i][j], 0, 0, 0);
      __builtin_amdgcn_s_setprio(0);
    }
  }

  // Epilogue: C/D layout row=(lane>>4)*4+r, col=lane&15
#pragma unroll
  for (int j = 0; j < NI; ++j) {
    const int col = col0 + wc * WN + (j << 4) + lq;
    const float bv = bias[col];
#pragma unroll
    for (int i = 0; i < MI; ++i) {
      const int rbase = row0 + wr * WM + (i << 4) + (seg << 2);
#pragma unroll
      for (int r = 0; r < 4; ++r)
        C[(size_t)(rbase + r) * N + col] = (TO)(acc[i][j][r] + bv);
    }
  }
}

// ---------------------------------------------------------------------------
// Per-q-tile flash state (one 16-row slice per wave).
// ---------------------------------------------------------------------------
struct QTile {
  bf16x8 qf[2];    // pre-scaled by SCALE*log2e
  f32x4  o[4];
  float  m[4], l[4];
};

__device__ __forceinline__ void qtile_init(QTile& st, const bf16* Qg,
                                           const int lq, const int seg) {
  const bf16x8 r0 = *(const bf16x8*)(Qg + (size_t)lq * QKV_LD + seg * 8);
  const bf16x8 r1 = *(const bf16x8*)(Qg + (size_t)lq * QKV_LD + 32 + seg * 8);
#pragma unroll
  for (int j = 0; j < 8; ++j) {
    st.qf[0][j] = (bf16)((float)r0[j] * SCALE2);
    st.qf[1][j] = (bf16)((float)r1[j] * SCALE2);
  }
  const f32x4 fz = {0.f, 0.f, 0.f, 0.f};
#pragma unroll
  for (int r = 0; r < 4; ++r) { st.o[r] = fz; st.m[r] = -1e30f; st.l[r] = 0.f; }
}

// QK^T -> mask -> online softmax (log2 domain, defer-max) -> P -> PV.
__device__ __forceinline__ void qtile_step(
    QTile& st, const int qb, const int nt,
    const int ws, const int lq, const int seg,
    const bf16 (&Ks)[64][64], const bf16 (&Vt)[64][64], bf16 (&Psw)[16][64])
{
  const f32x4 fz = {0.f, 0.f, 0.f, 0.f};
  f32x4 s[4];
  __builtin_amdgcn_s_setprio(1);
#pragma unroll
  for (int ct = 0; ct < 4; ++ct) {
    s[ct] = fz;
#pragma unroll
    for (int ks = 0; ks < 2; ++ks) {
      const int blk = ((ks << 2) + seg) ^ (lq & 7);
      const bf16x8 kf = *(const bf16x8*)(&Ks[(ct << 4) + lq][blk << 3]);
      s[ct] = __builtin_amdgcn_mfma_f32_16x16x32_bf16(st.qf[ks], kf, s[ct], 0, 0, 0);
    }
  }
  __builtin_amdgcn_s_setprio(0);

  // causal mask (diagonal tile only); scores already scaled via Q
  if (nt == qb) {
#pragma unroll
    for (int ct = 0; ct < 4; ++ct) {
      const int key = (nt << 6) + (ct << 4) + lq;
#pragma unroll
      for (int r = 0; r < 4; ++r) {
        const int qrow = (qb << 6) + (ws << 4) + (seg << 2) + r;
        if (key > qrow) s[ct][r] = -1e30f;
      }
    }
  }

  // online softmax, log2 domain, defer-max (skip rescale within THR)
#pragma unroll
  for (int r = 0; r < 4; ++r) {
    float tm = fmaxf(fmaxf(s[0][r], s[1][r]), fmaxf(s[2][r], s[3][r]));
    tm = red16_max(tm);
    if (tm > st.m[r] + DEFER_THR) {      // rescale path (rare)
      const float sc = fast_exp2(st.m[r] - tm);
      st.m[r] = tm;
      st.l[r] *= sc;
#pragma unroll
      for (int dt = 0; dt < 4; ++dt) st.o[dt][r] *= sc;
    }
    float rs = 0.f;
#pragma unroll
    for (int ct = 0; ct < 4; ++ct) {
      const float p = fast_exp2(s[ct][r] - st.m[r]);   // bounded by 2^THR
      s[ct][r] = p;
      rs += p;
    }
    rs = red16_sum(rs);
    st.l[r] += rs;
  }

  // P -> per-wave LDS (A-frag layout source), swizzled cols
#pragma unroll
  for (int ct = 0; ct < 4; ++ct)
#pragma unroll
    for (int r = 0; r < 4; ++r) {
      const int q = (seg << 2) + r;
      const int colp = ((ct << 4) + lq) ^ ((q & 7) << 3);
      Psw[q][colp] = (bf16)s[ct][r];
    }

  // PV: O += P[16][64] @ V[64][64]
  __builtin_amdgcn_s_setprio(1);
#pragma unroll
  for (int ks = 0; ks < 2; ++ks) {
    const int blkp = ((ks << 2) + seg) ^ (lq & 7);
    const bf16x8 af = *(const bf16x8*)(&Psw[lq][blkp << 3]);
#pragma unroll
    for (int dt = 0; dt < 4; ++dt) {
      const int xv = (lq & 7) ^ (((dt << 1) + (lq >> 3)) & 7);
      const int blkv = ((ks << 2) + seg) ^ xv;
      const bf16x8 bv = *(const bf16x8*)(&Vt[(dt << 4) + lq][blkv << 3]);
      st.o[dt] = __builtin_amdgcn_mfma_f32_16x16x32_bf16(af, bv, st.o[dt], 0, 0, 0);
    }
  }
  __builtin_amdgcn_s_setprio(0);
}

__device__ __forceinline__ void qtile_store(
    const QTile& st, bf16* __restrict__ out, const int qb, const int h,
    const int ws, const int lq, const int seg)
{
  float rinv[4];
#pragma unroll
  for (int r = 0; r < 4; ++r) rinv[r] = 1.f / st.l[r];
#pragma unroll
  for (int dt = 0; dt < 4; ++dt)
#pragma unroll
    for (int r = 0; r < 4; ++r) {
      const int qrow = (qb << 6) + (ws << 4) + (seg << 2) + r;
      out[(size_t)qrow * DM + h * HD + (dt << 4) + lq] =
          (bf16)(st.o[dt][r] * rinv[r]);
    }
}

// ---------------------------------------------------------------------------
// Flash-style causal attention, 8-wave blocks, wrap-paired q-tiles,
// XCD head-grouping (each XCD owns 4 heads -> KV stays in its L2),
// double-buffered KV with ONE barrier per tile (T14 write-late split).
// ---------------------------------------------------------------------------
__global__ __launch_bounds__(512, 4) void attn_flash(
    const bf16* __restrict__ qkv, bf16* __restrict__ out)
{
  __shared__ __align__(16) bf16 Ks[2][64][64];    // [buf][key][d], col-swizzled
  __shared__ __align__(16) bf16 Vt[2][64][64];    // [buf][d][key], key-swizzled
  __shared__ __align__(16) bf16 Ps[8][16][64];    // per-wave P, col-swizzled
  // XCD head-grouping: xcd = bid&7 serves heads 4*xcd..4*xcd+3
  const int bid = blockIdx.x;
  const int xcd = bid & 7, idx = bid >> 3;        // idx 0..63
  const int h   = (xcd << 2) | (idx >> 4);        // 4 heads per XCD
  const int qbA = idx & 15;                       // 0..15 (short range)
  const int qbB = 31 - qbA;                       // 31..16 (long range)
  const int tid = threadIdx.x;
  const int lane = tid & 63, wid = tid >> 6;      // wid 0..7
  const int lq = lane & 15, seg = lane >> 4;
  const int myqb = (wid < 4) ? qbA : qbB;
  const int ws   = wid & 3;                       // 16-row slice within tile

  const bf16* Kg = qkv + DM + h * HD;
  const bf16* Vg = qkv + 2 * DM + h * HD;

  QTile st;
  qtile_init(st, qkv + (size_t)(myqb * 64 + ws * 16) * QKV_LD + h * HD, lq, seg);

  const int srow = tid >> 3, sch = tid & 7;  // staging: row 0..63, chunk 0..7

  // prologue: tile 0 -> buf 0
  {
    const bf16x8 k0 = *(const bf16x8*)(Kg + (size_t)srow * QKV_LD + (sch << 3));
    const bf16x8 v0 = *(const bf16x8*)(Vg + (size_t)srow * QKV_LD + (sch << 3));
    *(bf16x8*)(&Ks[0][srow][(sch ^ (srow & 7)) << 3]) = k0;
#pragma unroll
    for (int j = 0; j < 8; ++j)
      Vt[0][(sch << 3) + j][srow ^ ((j ^ sch) << 3)] = v0[j];
  }
  __syncthreads();

  for (int nt = 0; nt <= qbB; ++nt) {
    // ---- issue next tile's global loads (fly during compute)
    bf16x8 kr, vr;
    if (nt < qbB) {
      const int row = ((nt + 1) << 6) + srow;
      kr = *(const bf16x8*)(Kg + (size_t)row * QKV_LD + (sch << 3));
      vr = *(const bf16x8*)(Vg + (size_t)row * QKV_LD + (sch << 3));
    }

    // ---- compute tile nt from buf[nt&1]
    if (nt <= myqb)
      qtile_step(st, myqb, nt, ws, lq, seg, Ks[nt & 1], Vt[nt & 1], Ps[wid]);

    // ---- write tile nt+1 into buf[(nt+1)&1] (reads of it ended last barrier)
    if (nt < qbB) {
      const int b = (nt + 1) & 1;
      *(bf16x8*)(&Ks[b][srow][(sch ^ (srow & 7)) << 3]) = kr;
#pragma unroll
      for (int j = 0; j < 8; ++j)
        Vt[b][(sch << 3) + j][srow ^ ((j ^ sch) << 3)] = vr[j];
    }
    __syncthreads();   // writes visible; reads of buf[nt&1] complete
  }

  qtile_store(st, out, myqb, h, ws, lq, seg);
}

// ---------------------------------------------------------------------------
extern "C" void kernel_launch(void* const* d_in, const int* in_sizes, int n_in,
                              void* d_out, int out_size, void* d_ws, size_t ws_size,
                              hipStream_t stream) {
  (void)in_sizes; (void)n_in; (void)out_size; (void)ws_size;
  const float* hidden = (const float*)d_in[0];
  const float* w_qkv  = (const float*)d_in[1];
  const float* b_qkv  = (const float*)d_in[2];
  const float* w_out  = (const float*)d_in[3];
  const float* b_out  = (const float*)d_in[4];
  float* out = (float*)d_out;

  bf16* qkvbuf  = (bf16*)d_ws;                            // [2048][6144]
  bf16* attnbuf = qkvbuf  + (size_t)S_LEN * (3 * DM);     // [2048][2048]
  bf16* hidb    = attnbuf + (size_t)S_LEN * DM;           // [2048][2048]
  bf16* wqkvb   = hidb    + (size_t)S_LEN * DM;           // [6144][2048]
  bf16* woutb   = wqkvb   + (size_t)(3 * DM) * DM;        // [2048][2048]

  dim3 blk(256);
  // fused f32 -> bf16 conversions (one launch)
  cvt3_f32_bf16<<<dim3(2048), blk, 0, stream>>>(
      hidden, hidb, (S_LEN * DM) / 8,
      w_qkv, wqkvb, (3 * DM * DM) / 8,
      w_out, woutb, (DM * DM) / 8);
  // QKV projection: 128x192 tiles, 512 blocks = 2/CU, counted-vmcnt pipeline
  gemm_pipe<128, 192, 2, 4, 512, 4, bf16><<<dim3(32, 16), dim3(512), 0, stream>>>(
      hidb, wqkvb, b_qkv, qkvbuf, S_LEN, 3 * DM, DM);
  // Flash causal attention: XCD head-grouped, paired q-tiles, KV dbuf
  attn_flash<<<dim3(512), dim3(512), 0, stream>>>(qkvbuf, attnbuf);
  // Output projection: 64x128 tiles, 512 blocks = 2/CU, counted-vmcnt pipeline
  gemm_pipe<64, 128, 1, 4, 256, 2, float><<<dim3(16, 32), dim3(256), 0, stream>>>(
      attnbuf, woutb, b_out, out, S_LEN, DM, DM);
}